// Round 16
// baseline (170.131 us; speedup 1.0000x reference)
//
#include <hip/hip_runtime.h>
#include <math.h>

#define BB 64
#define LL 128
#define HH 1024
#define EE 512
#define VV 32000
#define MAXV 33000

typedef float f32x4 __attribute__((ext_vector_type(4)));
typedef short bf16x8 __attribute__((ext_vector_type(8)));
typedef unsigned u32x4 __attribute__((ext_vector_type(4)));

__device__ __forceinline__ void gload_lds16(const void* g, void* l) {
    __builtin_amdgcn_global_load_lds((const __attribute__((address_space(1))) void*)g,
                                     (__attribute__((address_space(3))) void*)l, 16, 0, 0);
}

__device__ __forceinline__ unsigned short f2bf(float f) {
    unsigned u = __float_as_uint(f);
    return (unsigned short)((u + 0x7fffu + ((u >> 16) & 1u)) >> 16);
}

__device__ __forceinline__ unsigned pkbf(float a, float b) {
    unsigned r;
    asm("v_cvt_pk_bf16_f32 %0, %1, %2" : "=v"(r) : "v"(a), "v"(b));
    return r;
}

// fast exp/log/tanh (v_exp_f32 / v_log_f32 paths), err ~1e-6 rel
__device__ __forceinline__ float fexp(float x) { return __expf(x); }
__device__ __forceinline__ float flog(float x) { return __logf(x); }
__device__ __forceinline__ float ftanh(float x) { return 1.f - 2.f / (1.f + __expf(2.f * x)); }

__device__ __forceinline__ void smerge(float& m, float& s, float m2, float s2) {
    float nm = fmaxf(m, m2);
    s = s * fexp(m - nm) + s2 * fexp(m2 - nm);
    m = nm;
}

// ---------------- SETUP2: cvt enc->bf16 | cvt WcW->bf16 | build xaB | bias-preinit | zeros | zero out1 ----------------
#define N_ENC4 2097152
__global__ void setup2(const float* __restrict__ enc, unsigned short* __restrict__ encB,
                       const float* __restrict__ WcW, unsigned short* __restrict__ WcB,
                       const int* __restrict__ tok, const float* __restrict__ hidden,
                       const float* __restrict__ emb, unsigned short* __restrict__ xaB,
                       const float* __restrict__ attnb, const float* __restrict__ combb,
                       const float* __restrict__ bih, const float* __restrict__ bhh,
                       float* __restrict__ aT, float* __restrict__ gruOutF,
                       float* __restrict__ giT, float* __restrict__ ghT,
                       float* __restrict__ zeros, float* __restrict__ out1) {
    int idx = blockIdx.x * 256 + threadIdx.x;   // 3575808 total
    if (idx < N_ENC4) {
        float4 v = ((const float4*)enc)[idx];
        ushort4 o;
        o.x = f2bf(v.x); o.y = f2bf(v.y); o.z = f2bf(v.z); o.w = f2bf(v.w);
        ((ushort4*)encB)[idx] = o;
        return;
    }
    idx -= N_ENC4;
    if (idx < 262144) {
        float4 v = ((const float4*)WcW)[idx];
        ushort4 o;
        o.x = f2bf(v.x); o.y = f2bf(v.y); o.z = f2bf(v.z); o.w = f2bf(v.w);
        ((ushort4*)WcB)[idx] = o;
        return;
    }
    idx -= 262144;
    if (idx < 98304) {
        int b = idx / 1536, k = idx % 1536;
        float v = (k < EE) ? emb[tok[b] * EE + k] : hidden[b * HH + (k - EE)];
        xaB[b * 1536 + k] = f2bf(v);
        return;
    }
    idx -= 98304;
    if (idx < 8192) { aT[idx] = attnb[idx >> 6]; return; }
    idx -= 8192;
    if (idx < 65536) { gruOutF[idx] = combb[idx >> 6]; return; }
    idx -= 65536;
    if (idx < 196608) { giT[idx] = bih[idx >> 6]; return; }
    idx -= 196608;
    if (idx < 196608) { ghT[idx] = bhh[idx >> 6]; return; }
    idx -= 196608;
    if (idx < 139264) { zeros[idx] = 0.f; return; }
    idx -= 139264;
    int b = idx / 8000, q = idx % 8000;
    ((float4*)(out1 + (size_t)b * MAXV))[q] = (float4){0.f, 0.f, 0.f, 0.f};
}

// ---------------- mgemm body: out[r][b] = sum_k W[r][k] * x[b][k]  (x bf16, W f32->bf16 in-reg) ----------------
template <int DIRECT, int MI>
__device__ __forceinline__ void mgemm_body(int bid,
        const float* __restrict__ W, const float* __restrict__ bias,
        const unsigned short* __restrict__ xA, int sA,
        const unsigned short* __restrict__ xB, int sB, int K1,
        int K, int Kc, int splitk, float* __restrict__ out) {
    int tid = threadIdx.x, w = tid >> 6, lane = tid & 63;
    int rb = bid / splitk, kseg = bid - rb * splitk;
    int r0 = rb * (MI * 64), kb0 = kseg * Kc;
    int lr = lane & 15, lk = lane >> 4;
    int nt = Kc >> 6;
    f32x4 acc[MI][4];
#pragma unroll
    for (int mi = 0; mi < MI; ++mi)
#pragma unroll
        for (int nf = 0; nf < 4; ++nf) acc[mi][nf] = (f32x4){0.f, 0.f, 0.f, 0.f};
    const float* Wr[MI];
#pragma unroll
    for (int mi = 0; mi < MI; ++mi)
        Wr[mi] = W + (size_t)(r0 + w * (MI * 16) + mi * 16 + lr) * K;

    for (int t = 0; t < nt; ++t) {
        int kb = kb0 + t * 64;
        bf16x8 bfr[2][4];
#pragma unroll
        for (int ks = 0; ks < 2; ++ks)
#pragma unroll
            for (int nf = 0; nf < 4; ++nf) {
                int bcol = nf * 16 + lr;
                int kg = kb + ks * 32 + lk * 8;
                const unsigned short* xp = (kg < K1) ? (xA + bcol * sA + kg)
                                                     : (xB + bcol * sB + (kg - K1));
                bfr[ks][nf] = *(const bf16x8*)xp;
            }
        bf16x8 afr[MI][2];
#pragma unroll
        for (int mi = 0; mi < MI; ++mi)
#pragma unroll
            for (int ks = 0; ks < 2; ++ks) {
                const float* wp = Wr[mi] + kb + ks * 32 + lk * 8;
                float4 w0 = *(const float4*)wp;
                float4 w1 = *(const float4*)(wp + 4);
                union { u32x4 u; bf16x8 h; } cv;
                cv.u[0] = pkbf(w0.x, w0.y); cv.u[1] = pkbf(w0.z, w0.w);
                cv.u[2] = pkbf(w1.x, w1.y); cv.u[3] = pkbf(w1.z, w1.w);
                afr[mi][ks] = cv.h;
            }
#pragma unroll
        for (int ks = 0; ks < 2; ++ks)
#pragma unroll
            for (int mi = 0; mi < MI; ++mi)
#pragma unroll
                for (int nf = 0; nf < 4; ++nf)
                    acc[mi][nf] = __builtin_amdgcn_mfma_f32_16x16x32_bf16(
                        afr[mi][ks], bfr[ks][nf], acc[mi][nf], 0, 0, 0);
    }
#pragma unroll
    for (int mi = 0; mi < MI; ++mi)
#pragma unroll
        for (int nf = 0; nf < 4; ++nf)
#pragma unroll
            for (int reg = 0; reg < 4; ++reg) {
                int r = r0 + w * (MI * 16) + mi * 16 + lk * 4 + reg;
                int bcol = nf * 16 + lr;
                float v = acc[mi][nf][reg];
                if (DIRECT) out[r * 64 + bcol] = v + bias[r];
                else atomicAdd(&out[r * 64 + bcol], v);
            }
}

template <int DIRECT, int MI>
__global__ __launch_bounds__(256) void mgemm(
        const float* __restrict__ W, const float* __restrict__ bias,
        const unsigned short* __restrict__ xA, int sA,
        const unsigned short* __restrict__ xB, int sB, int K1,
        int K, int Kc, int splitk, float* __restrict__ out) {
    mgemm_body<DIRECT, MI>(blockIdx.x, W, bias, xA, sA, xB, sB, K1, K, Kc, splitk, out);
}

// ---------------- merged GRU GEMMs: blocks 0..191 Wih (splitk 8), 192..383 Whh (splitk 8) ----------------
__global__ __launch_bounds__(256) void gru2(
        const float* __restrict__ Wih, const float* __restrict__ Whh,
        const unsigned short* __restrict__ gruInB, const unsigned short* __restrict__ xaB512,
        float* __restrict__ giT, float* __restrict__ ghT) {
    const float* W; const unsigned short* x; int s, K1, K, Kc; float* out; int bid;
    if (blockIdx.x < 192) { W = Wih; x = gruInB; s = 2048; K1 = 2048; K = 2048; Kc = 256; out = giT; bid = blockIdx.x; }
    else                  { W = Whh; x = xaB512; s = 1536; K1 = 1024; K = 1024; Kc = 128; out = ghT; bid = blockIdx.x - 192; }
    mgemm_body<0, 2>(bid, W, nullptr, x, s, x, s, K1, K, Kc, 8, out);
}

// ---------------- K2: softmax(a) + sel; stream enc over an L-chunk (16 rows), atomic partials ----------------
__global__ __launch_bounds__(256) void k2_softmax_enc(
        const float* __restrict__ aT, const int* __restrict__ tok, const int* __restrict__ seq,
        const float* __restrict__ pprob, const float* __restrict__ enc,
        float* __restrict__ ap4T, float* __restrict__ gruSelF, float* __restrict__ out3) {
    int b = blockIdx.x, lc = blockIdx.y, t = threadIdx.x;
    __shared__ float red[256];
    __shared__ float w_s[16], sel_s[16];
    float av = (t < LL) ? aT[t * 64 + b] : -1e30f;
    red[t] = av; __syncthreads();
    for (int s = 128; s > 0; s >>= 1) { if (t < s) red[t] = fmaxf(red[t], red[t + s]); __syncthreads(); }
    float m = red[0]; __syncthreads();
    float e = (t < LL) ? fexp(av - m) : 0.f;
    red[t] = e; __syncthreads();
    for (int s = 128; s > 0; s >>= 1) { if (t < s) red[t] += red[t + s]; __syncthreads(); }
    float Z = red[0]; __syncthreads();
    if (t < LL) {
        float wv = e / Z;
        if (lc == 0) out3[b * LL + t] = wv;
        int l0 = lc * 16;
        if (t >= l0 && t < l0 + 16) {
            w_s[t - l0] = wv;
            sel_s[t - l0] = (seq[b * LL + t] == tok[b]) ? pprob[b * LL + t] : 0.f;
        }
    }
    __syncthreads();
    float accA[4] = {0.f,0.f,0.f,0.f}, accS[4] = {0.f,0.f,0.f,0.f};
    const float* encb = enc + (size_t)b * LL * HH + (size_t)lc * 16 * HH;
    for (int l = 0; l < 16; ++l) {
        float wl = w_s[l], sl = sel_s[l];
#pragma unroll
        for (int i = 0; i < 4; ++i) {
            float ev = encb[l * HH + t + i * 256];
            accA[i] += wl * ev;
            accS[i] += sl * truncf(ev);
        }
    }
#pragma unroll
    for (int i = 0; i < 4; ++i) {
        int h = t + i * 256;
        atomicAdd(&ap4T[(h >> 2) * 256 + b * 4 + (h & 3)], accA[i]);
        atomicAdd(&gruSelF[(h >> 2) * 256 + b * 4 + (h & 3)], accS[i]);
    }
}

// ---------------- cvt_ap: ap4T (f32 4T) -> apB[b][k] bf16 ----------------
__global__ void cvt_ap(const float* __restrict__ ap4T, unsigned short* __restrict__ apB) {
    int tid = blockIdx.x * 256 + threadIdx.x;  // 16384
    int b = tid & 63, kq = tid >> 6;
    float4 v = *(const float4*)&ap4T[kq * 256 + b * 4];
    ushort4 o;
    o.x = f2bf(v.x); o.y = f2bf(v.y); o.z = f2bf(v.z); o.w = f2bf(v.w);
    *(ushort4*)&apB[b * 1024 + kq * 4] = o;
}

// ---------------- cvt_gruIn: [relu(gruOutF); gruSelF] -> gruInB[b][0..2048) bf16 ----------------
__global__ void cvt_gruIn(const float* __restrict__ gruOutF, const float* __restrict__ gruSelF,
                          unsigned short* __restrict__ gruInB) {
    int tid = blockIdx.x * 256 + threadIdx.x;  // 32768
    int b = tid & 63, kq = tid >> 6;
    float4 v;
    if (kq < 256) {
        int k = kq * 4;
        v.x = fmaxf(gruOutF[(k + 0) * 64 + b], 0.f);
        v.y = fmaxf(gruOutF[(k + 1) * 64 + b], 0.f);
        v.z = fmaxf(gruOutF[(k + 2) * 64 + b], 0.f);
        v.w = fmaxf(gruOutF[(k + 3) * 64 + b], 0.f);
    } else {
        v = *(const float4*)&gruSelF[(kq - 256) * 256 + b * 4];
    }
    ushort4 o;
    o.x = f2bf(v.x); o.y = f2bf(v.y); o.z = f2bf(v.z); o.w = f2bf(v.w);
    *(ushort4*)&gruInB[b * 2048 + kq * 4] = o;
}

// ---------------- K5: GRU gates -> h_new ----------------
__global__ void k5_gates(const float* __restrict__ giT, const float* __restrict__ ghT,
                         const float* __restrict__ hidden, float* __restrict__ hn4T,
                         unsigned short* __restrict__ hnB, float* __restrict__ out2) {
    int idx = blockIdx.x * 256 + threadIdx.x;   // 65536
    int r = idx >> 6, b = idx & 63;
    float ir = giT[r * 64 + b], iz = giT[(HH + r) * 64 + b], in_ = giT[(2 * HH + r) * 64 + b];
    float hr = ghT[r * 64 + b], hz = ghT[(HH + r) * 64 + b], hn = ghT[(2 * HH + r) * 64 + b];
    float rr = 1.f / (1.f + fexp(-(ir + hr)));
    float zz = 1.f / (1.f + fexp(-(iz + hz)));
    float nn = ftanh(in_ + rr * hn);
    float hprev = hidden[b * HH + r];
    float hnew = (1.f - zz) * nn + zz * hprev;
    hn4T[(r >> 2) * 256 + b * 4 + (r & 3)] = hnew;
    hnB[b * 1024 + r] = f2bf(hnew);
    out2[b * HH + r] = hnew;
}

// ---------------- WOW_F1: WoW GEMM, 32 rows/block x 1000 blocks; LDS-staged contiguous W
// (XOR-pre-swizzled source), ~4 blocks/CU for barrier-drain overlap; fused f1 partial ----------------
__global__ __launch_bounds__(256) void wow_f1(
        const float* __restrict__ WoW, const float* __restrict__ Wob,
        const unsigned short* __restrict__ hnB, float* __restrict__ sgT,
        float* __restrict__ partMt, float* __restrict__ partSt) {
    __shared__ __align__(16) float Ws[32 * 64];   // 8 KB: 32 rows x 16 chunks(16B)
    __shared__ float pm_s[2 * 64], ps_s[2 * 64];
    int tid = threadIdx.x, w = tid >> 6, lane = tid & 63;
    int lr = lane & 15, lk = lane >> 4;
    int rw = w & 1, cw = w >> 1;                  // row-half (16 rows), col-half (32 batch)
    int r0 = blockIdx.x * 32;
    int arow = rw * 16 + lr;                      // A-fragment row this lane serves (0..31)
    int sw = arow & 7;                            // read-side XOR key
    f32x4 acc[2];
    acc[0] = (f32x4){0.f, 0.f, 0.f, 0.f};
    acc[1] = (f32x4){0.f, 0.f, 0.f, 0.f};

    for (int kt = 0; kt < 16; ++kt) {
        __syncthreads();
        // stage W tile: 512 16B chunks; dest linear, source chunk pre-swizzled (ch ^ (row&7))
        {
            int c = tid;                          // i = 0
            int row = c >> 4, ch = c & 15;
            int chs = ch ^ (row & 7);
            gload_lds16(WoW + (size_t)(r0 + row) * HH + kt * 64 + chs * 4,
                        (char*)Ws + (w * 64) * 16);
            c = 256 + tid;                        // i = 1
            row = c >> 4; ch = c & 15;
            chs = ch ^ (row & 7);
            gload_lds16(WoW + (size_t)(r0 + row) * HH + kt * 64 + chs * 4,
                        (char*)Ws + (256 + w * 64) * 16);
        }
        // B fragments (hnB is 128 KB, L2-hot) while staging is in flight
        int kb = kt * 64;
        bf16x8 bfr[2][2];
#pragma unroll
        for (int ks = 0; ks < 2; ++ks)
#pragma unroll
            for (int nf = 0; nf < 2; ++nf)
                bfr[ks][nf] = *(const bf16x8*)(hnB + (cw * 32 + nf * 16 + lr) * 1024 + kb + ks * 32 + lk * 8);
        asm volatile("s_waitcnt vmcnt(0)");
        __syncthreads();
        // A fragments from LDS (swizzled chunks) -> cvt to bf16
        bf16x8 afr[2];
#pragma unroll
        for (int ks = 0; ks < 2; ++ks) {
            int c0 = (ks * 8 + lk * 2) ^ sw;
            int c1 = (ks * 8 + lk * 2 + 1) ^ sw;
            float4 w0 = *(const float4*)((const char*)Ws + (arow * 16 + c0) * 16);
            float4 w1 = *(const float4*)((const char*)Ws + (arow * 16 + c1) * 16);
            union { u32x4 u; bf16x8 h; } cv;
            cv.u[0] = pkbf(w0.x, w0.y); cv.u[1] = pkbf(w0.z, w0.w);
            cv.u[2] = pkbf(w1.x, w1.y); cv.u[3] = pkbf(w1.z, w1.w);
            afr[ks] = cv.h;
        }
#pragma unroll
        for (int ks = 0; ks < 2; ++ks)
#pragma unroll
            for (int nf = 0; nf < 2; ++nf)
                acc[nf] = __builtin_amdgcn_mfma_f32_16x16x32_bf16(afr[ks], bfr[ks][nf], acc[nf], 0, 0, 0);
    }
    // epilogue: bias, store sgT, fused per-batch online (m,s) partial over 32 rows
#pragma unroll
    for (int nf = 0; nf < 2; ++nf) {
        int bcol = cw * 32 + nf * 16 + lr;
        float m = -1e30f, s = 0.f;
#pragma unroll
        for (int reg = 0; reg < 4; ++reg) {
            int r = r0 + rw * 16 + lk * 4 + reg;
            float v = acc[nf][reg] + Wob[r];
            sgT[r * 64 + bcol] = v;
            float nm = fmaxf(m, v);
            s = s * fexp(m - nm) + fexp(v - nm);
            m = nm;
        }
        // merge the 4 lk groups (16 rows of this wave)
#pragma unroll
        for (int d = 16; d <= 32; d <<= 1) {
            float om = __shfl_xor(m, d), os = __shfl_xor(s, d);
            smerge(m, s, om, os);
        }
        if (lk == 0) { pm_s[rw * 64 + bcol] = m; ps_s[rw * 64 + bcol] = s; }
    }
    __syncthreads();
    if (tid < 64) {
        float m = pm_s[tid], s = ps_s[tid];
        smerge(m, s, pm_s[64 + tid], ps_s[64 + tid]);
        partMt[tid * 1024 + blockIdx.x] = m;
        partSt[tid * 1024 + blockIdx.x] = s;
    }
}

// ---------------- K7: MFMA bf16 GEMM + fused tanh*h reduce -> sc (128x128, single-buffer, XCD swizzle) ----------------
__global__ __launch_bounds__(256) void k7_mfma(const unsigned short* __restrict__ encB,
        const unsigned short* __restrict__ WcB, const float* __restrict__ Wcb,
        const float* __restrict__ hn4T, float* __restrict__ sc) {
    __shared__ __align__(16) unsigned short As[128 * 64];
    __shared__ __align__(16) unsigned short Bs[128 * 64];
    __shared__ float h_s[128], bias_s[128];
    int tid = threadIdx.x, w = tid >> 6, lane = tid & 63;
    int wm = w >> 1, wn = w & 1;
    int bid = blockIdx.x;
    int swz = (bid & 7) * 64 + (bid >> 3);   // bijective XCD swizzle, 512 = 8*64
    int mt = swz >> 3, nt = swz & 7;
    int m0 = mt * 128, n0 = nt * 128;
    if (tid < 128) {
        int n = n0 + tid;
        bias_s[tid] = Wcb[n];
        h_s[tid] = hn4T[(n >> 2) * 256 + mt * 4 + (n & 3)];
    }
    f32x4 acc[4][4];
#pragma unroll
    for (int mi = 0; mi < 4; ++mi)
#pragma unroll
        for (int ni = 0; ni < 4; ++ni) acc[mi][ni] = (f32x4){0.f, 0.f, 0.f, 0.f};

    for (int kt = 0; kt < 16; ++kt) {
        __syncthreads();
#pragma unroll
        for (int i = 0; i < 4; ++i) {
            int c = i * 256 + tid;
            int row = c >> 3, cc = c & 7;
            int lc2 = cc ^ (row & 7);
            gload_lds16(encB + (size_t)(m0 + row) * HH + kt * 64 + lc2 * 8,
                        (char*)As + (i * 256 + w * 64) * 16);
        }
#pragma unroll
        for (int i = 0; i < 4; ++i) {
            int c = i * 256 + tid;
            int row = c >> 3, cc = c & 7;
            int lc2 = cc ^ (row & 7);
            gload_lds16(WcB + (size_t)(n0 + row) * HH + kt * 64 + lc2 * 8,
                        (char*)Bs + (i * 256 + w * 64) * 16);
        }
        asm volatile("s_waitcnt vmcnt(0)");
        __syncthreads();
#pragma unroll
        for (int ks = 0; ks < 2; ++ks) {
            bf16x8 af[4], bf[4];
#pragma unroll
            for (int mi = 0; mi < 4; ++mi) {
                int rr = wm * 64 + mi * 16 + (lane & 15);
                int lkk = ks * 4 + (lane >> 4);
                af[mi] = *(const bf16x8*)((const char*)As + rr * 128 + ((lkk ^ (rr & 7)) * 16));
            }
#pragma unroll
            for (int ni = 0; ni < 4; ++ni) {
                int rr = wn * 64 + ni * 16 + (lane & 15);
                int lkk = ks * 4 + (lane >> 4);
                bf[ni] = *(const bf16x8*)((const char*)Bs + rr * 128 + ((lkk ^ (rr & 7)) * 16));
            }
#pragma unroll
            for (int mi = 0; mi < 4; ++mi)
#pragma unroll
                for (int ni = 0; ni < 4; ++ni)
                    acc[mi][ni] = __builtin_amdgcn_mfma_f32_16x16x32_bf16(af[mi], bf[ni], acc[mi][ni], 0, 0, 0);
        }
    }
    float rs[16];
#pragma unroll
    for (int z = 0; z < 16; ++z) rs[z] = 0.f;
#pragma unroll
    for (int ni = 0; ni < 4; ++ni) {
        int nl = wn * 64 + ni * 16 + (lane & 15);
        float hv = h_s[nl], bv = bias_s[nl];
#pragma unroll
        for (int mi = 0; mi < 4; ++mi)
#pragma unroll
            for (int reg = 0; reg < 4; ++reg)
                rs[mi * 4 + reg] += ftanh(acc[mi][ni][reg] + bv) * hv;
    }
#pragma unroll
    for (int z = 0; z < 16; ++z) {
        float v = rs[z];
        v += __shfl_xor(v, 1); v += __shfl_xor(v, 2);
        v += __shfl_xor(v, 4); v += __shfl_xor(v, 8);
        rs[z] = v;
    }
    if ((lane & 15) == 0) {
        int g = lane >> 4;
#pragma unroll
        for (int mi = 0; mi < 4; ++mi)
#pragma unroll
            for (int reg = 0; reg < 4; ++reg)
                atomicAdd(&sc[mt * LL + wm * 64 + mi * 16 + g * 4 + reg], rs[mi * 4 + reg]);
    }
}

// ---------------- F1c: tree-combine partials + sc -> M,Z ; write out4 + scatter into out1 ----------------
__global__ __launch_bounds__(256) void f1c_final(const float* __restrict__ partMt,
        const float* __restrict__ partSt, const float* __restrict__ sc,
        const int* __restrict__ seq, float* __restrict__ Mb, float* __restrict__ Zb,
        float* __restrict__ out4, float* __restrict__ out1) {
    int b = blockIdx.x, t = threadIdx.x;
    __shared__ float mred[256], sred[256];
    float m = -1e30f, s = 0.f;
    for (int w = t; w < 1000; w += 256)
        smerge(m, s, partMt[b * 1024 + w], partSt[b * 1024 + w]);
    if (t < 128) smerge(m, s, sc[b * LL + t], 1.0f);
    mred[t] = m; sred[t] = s; __syncthreads();
    for (int st = 128; st > 0; st >>= 1) {
        if (t < st) {
            float mm = mred[t], ss = sred[t];
            smerge(mm, ss, mred[t + st], sred[t + st]);
            mred[t] = mm; sred[t] = ss;
        }
        __syncthreads();
    }
    float M = mred[0], Z = sred[0];
    if (t == 0) { Mb[b] = M; Zb[b] = Z; }
    if (t < 128) {
        float p = fexp(sc[b * LL + t] - M) / Z;
        out4[b * LL + t] = p;
        atomicAdd(&out1[(size_t)b * MAXV + seq[b * LL + t]], p);
    }
}

// ---------------- F2F4: prob_g + scatter-sum, floor, col2, log -> out1 (single pass) ----------------
__global__ void f2f4_final(const float* __restrict__ sgT, const float* __restrict__ Mb,
                           const float* __restrict__ Zb, float* __restrict__ out1) {
    int b = blockIdx.y;
    int v = blockIdx.x * 256 + threadIdx.x;
    if (v >= MAXV) return;
    float val = 0.f;
    if (v < VV) {
        float scat = out1[(size_t)b * MAXV + v];
        val = fexp(sgT[v * 64 + b] - Mb[b]) / Zb[b] + scat;
    }
    if (v == 2 || val == 0.f) val = 1e-9f;
    out1[(size_t)b * MAXV + v] = flog(val);
}

extern "C" void kernel_launch(void* const* d_in, const int* in_sizes, int n_in,
                              void* d_out, int out_size, void* d_ws, size_t ws_size,
                              hipStream_t stream) {
    (void)in_sizes; (void)n_in; (void)out_size; (void)ws_size;
    const int*   tok    = (const int*)  d_in[0];
    const float* hidden = (const float*)d_in[1];
    const float* enc    = (const float*)d_in[2];
    const int*   seq    = (const int*)  d_in[3];
    const float* pprob  = (const float*)d_in[4];
    const float* emb    = (const float*)d_in[5];
    const float* attnW  = (const float*)d_in[6];
    const float* attnb  = (const float*)d_in[7];
    const float* combW  = (const float*)d_in[8];
    const float* combb  = (const float*)d_in[9];
    const float* Wih    = (const float*)d_in[10];
    const float* Whh    = (const float*)d_in[11];
    const float* bih    = (const float*)d_in[12];
    const float* bhh    = (const float*)d_in[13];
    const float* WoW    = (const float*)d_in[14];
    const float* Wob    = (const float*)d_in[15];
    const float* WcW    = (const float*)d_in[16];
    const float* Wcb    = (const float*)d_in[17];

    float* out1 = (float*)d_out;
    float* out2 = out1 + (size_t)BB * MAXV;
    float* out3 = out2 + BB * HH;
    float* out4 = out3 + BB * LL;

    float* ws      = (float*)d_ws;
    float* aT      = ws;                    // 8192
    float* ap4T    = ws + 8192;             // 65536  (zero region start)
    float* gruSelF = ws + 73728;            // 65536
    float* sc      = ws + 139264;           // 8192   (zero region len 139264)
    float* gruOutF = ws + 147456;           // 65536
    float* giT     = ws + 212992;           // 196608
    float* ghT     = ws + 409600;           // 196608
    float* hn4T    = ws + 606208;           // 65536
    float* sgT     = ws + 671744;           // 2048000
    float* partMt  = ws + 2719744;          // 65536 (64 x 1024)
    float* partSt  = ws + 2785280;          // 65536
    float* Mb      = ws + 2850816;          // 64
    float* Zb      = ws + 2850880;          // 64
    unsigned short* encB = (unsigned short*)(ws + 2850944);   // 8388608 bf16 -> f 7045248
    unsigned short* WcB  = encB + 8388608;                    // 1048576 bf16 -> f 7569536
    unsigned short* hnB  = (unsigned short*)(ws + 7569536);   // 65536 bf16 -> f 7602304
    // transient bf16 x-buffers inside sgT region (consumed before sgT is written)
    unsigned short* xaB    = (unsigned short*)sgT;            // 98304 bf16 (f 671744..720896)
    unsigned short* apB    = (unsigned short*)(ws + 720896);  // 65536 bf16 (..753664)
    unsigned short* gruInB = (unsigned short*)(ws + 753664);  // 131072 bf16 (..819200)

    setup2       <<<13968, 256, 0, stream>>>(enc, encB, WcW, WcB, tok, hidden, emb, xaB,
                                             attnb, combb, bih, bhh,
                                             aT, gruOutF, giT, ghT, ap4T, out1);
    mgemm<0,2>   <<<12, 256, 0, stream>>>(attnW, nullptr, xaB, 1536, xaB, 1536, 1536, 1536, 128, 12, aT);
    k2_softmax_enc<<<dim3(64, 8), 256, 0, stream>>>(aT, tok, seq, pprob, enc, ap4T, gruSelF, out3);
    cvt_ap       <<<64, 256, 0, stream>>>(ap4T, apB);
    mgemm<0,2>   <<<96, 256, 0, stream>>>(combW, nullptr, xaB, 1536, apB, 1024, 512, 1536, 128, 12, gruOutF);
    cvt_gruIn    <<<128, 256, 0, stream>>>(gruOutF, gruSelF, gruInB);
    gru2         <<<384, 256, 0, stream>>>(Wih, Whh, gruInB, xaB + 512, giT, ghT);
    k5_gates     <<<256, 256, 0, stream>>>(giT, ghT, hidden, hn4T, hnB, out2);
    wow_f1       <<<1000, 256, 0, stream>>>(WoW, Wob, hnB, sgT, partMt, partSt);
    k7_mfma      <<<512, 256, 0, stream>>>(encB, WcB, Wcb, hn4T, sc);
    f1c_final    <<<64, 256, 0, stream>>>(partMt, partSt, sc, seq, Mb, Zb, out4, out1);
    f2f4_final   <<<dim3(129, 64), 256, 0, stream>>>(sgT, Mb, Zb, out1);
}

// Round 17
// 167.488 us; speedup vs baseline: 1.0158x; 1.0158x over previous
//
#include <hip/hip_runtime.h>
#include <math.h>

#define BB 64
#define LL 128
#define HH 1024
#define EE 512
#define VV 32000
#define MAXV 33000

typedef float f32x4 __attribute__((ext_vector_type(4)));
typedef short bf16x8 __attribute__((ext_vector_type(8)));
typedef unsigned u32x4 __attribute__((ext_vector_type(4)));

__device__ __forceinline__ void gload_lds16(const void* g, void* l) {
    __builtin_amdgcn_global_load_lds((const __attribute__((address_space(1))) void*)g,
                                     (__attribute__((address_space(3))) void*)l, 16, 0, 0);
}

__device__ __forceinline__ unsigned short f2bf(float f) {
    unsigned u = __float_as_uint(f);
    return (unsigned short)((u + 0x7fffu + ((u >> 16) & 1u)) >> 16);
}

__device__ __forceinline__ unsigned pkbf(float a, float b) {
    unsigned r;
    asm("v_cvt_pk_bf16_f32 %0, %1, %2" : "=v"(r) : "v"(a), "v"(b));
    return r;
}

// fast exp/log/tanh (v_exp_f32 / v_log_f32 paths), err ~1e-6 rel
__device__ __forceinline__ float fexp(float x) { return __expf(x); }
__device__ __forceinline__ float flog(float x) { return __logf(x); }
__device__ __forceinline__ float ftanh(float x) { return 1.f - 2.f / (1.f + __expf(2.f * x)); }

__device__ __forceinline__ void smerge(float& m, float& s, float m2, float s2) {
    float nm = fmaxf(m, m2);
    s = s * fexp(m - nm) + s2 * fexp(m2 - nm);
    m = nm;
}

// ---------------- SETUP2: cvt enc->bf16 | cvt WcW->bf16 | build xaB | bias-preinit | zeros | zero out1 ----------------
#define N_ENC4 2097152
__global__ void setup2(const float* __restrict__ enc, unsigned short* __restrict__ encB,
                       const float* __restrict__ WcW, unsigned short* __restrict__ WcB,
                       const int* __restrict__ tok, const float* __restrict__ hidden,
                       const float* __restrict__ emb, unsigned short* __restrict__ xaB,
                       const float* __restrict__ attnb, const float* __restrict__ combb,
                       const float* __restrict__ bih, const float* __restrict__ bhh,
                       float* __restrict__ aT, float* __restrict__ gruOutF,
                       float* __restrict__ giT, float* __restrict__ ghT,
                       float* __restrict__ zeros, float* __restrict__ out1) {
    int idx = blockIdx.x * 256 + threadIdx.x;   // 3575808 total
    if (idx < N_ENC4) {
        float4 v = ((const float4*)enc)[idx];
        ushort4 o;
        o.x = f2bf(v.x); o.y = f2bf(v.y); o.z = f2bf(v.z); o.w = f2bf(v.w);
        ((ushort4*)encB)[idx] = o;
        return;
    }
    idx -= N_ENC4;
    if (idx < 262144) {
        float4 v = ((const float4*)WcW)[idx];
        ushort4 o;
        o.x = f2bf(v.x); o.y = f2bf(v.y); o.z = f2bf(v.z); o.w = f2bf(v.w);
        ((ushort4*)WcB)[idx] = o;
        return;
    }
    idx -= 262144;
    if (idx < 98304) {
        int b = idx / 1536, k = idx % 1536;
        float v = (k < EE) ? emb[tok[b] * EE + k] : hidden[b * HH + (k - EE)];
        xaB[b * 1536 + k] = f2bf(v);
        return;
    }
    idx -= 98304;
    if (idx < 8192) { aT[idx] = attnb[idx >> 6]; return; }
    idx -= 8192;
    if (idx < 65536) { gruOutF[idx] = combb[idx >> 6]; return; }
    idx -= 65536;
    if (idx < 196608) { giT[idx] = bih[idx >> 6]; return; }
    idx -= 196608;
    if (idx < 196608) { ghT[idx] = bhh[idx >> 6]; return; }
    idx -= 196608;
    if (idx < 139264) { zeros[idx] = 0.f; return; }
    idx -= 139264;
    int b = idx / 8000, q = idx % 8000;
    ((float4*)(out1 + (size_t)b * MAXV))[q] = (float4){0.f, 0.f, 0.f, 0.f};
}

// ---------------- mgemm body: out[r][b] = sum_k W[r][k] * x[b][k]  (x bf16, W f32->bf16 in-reg) ----------------
template <int DIRECT, int MI>
__device__ __forceinline__ void mgemm_body(int bid,
        const float* __restrict__ W, const float* __restrict__ bias,
        const unsigned short* __restrict__ xA, int sA,
        const unsigned short* __restrict__ xB, int sB, int K1,
        int K, int Kc, int splitk, float* __restrict__ out) {
    int tid = threadIdx.x, w = tid >> 6, lane = tid & 63;
    int rb = bid / splitk, kseg = bid - rb * splitk;
    int r0 = rb * (MI * 64), kb0 = kseg * Kc;
    int lr = lane & 15, lk = lane >> 4;
    int nt = Kc >> 6;
    f32x4 acc[MI][4];
#pragma unroll
    for (int mi = 0; mi < MI; ++mi)
#pragma unroll
        for (int nf = 0; nf < 4; ++nf) acc[mi][nf] = (f32x4){0.f, 0.f, 0.f, 0.f};
    const float* Wr[MI];
#pragma unroll
    for (int mi = 0; mi < MI; ++mi)
        Wr[mi] = W + (size_t)(r0 + w * (MI * 16) + mi * 16 + lr) * K;

    for (int t = 0; t < nt; ++t) {
        int kb = kb0 + t * 64;
        bf16x8 bfr[2][4];
#pragma unroll
        for (int ks = 0; ks < 2; ++ks)
#pragma unroll
            for (int nf = 0; nf < 4; ++nf) {
                int bcol = nf * 16 + lr;
                int kg = kb + ks * 32 + lk * 8;
                const unsigned short* xp = (kg < K1) ? (xA + bcol * sA + kg)
                                                     : (xB + bcol * sB + (kg - K1));
                bfr[ks][nf] = *(const bf16x8*)xp;
            }
        bf16x8 afr[MI][2];
#pragma unroll
        for (int mi = 0; mi < MI; ++mi)
#pragma unroll
            for (int ks = 0; ks < 2; ++ks) {
                const float* wp = Wr[mi] + kb + ks * 32 + lk * 8;
                float4 w0 = *(const float4*)wp;
                float4 w1 = *(const float4*)(wp + 4);
                union { u32x4 u; bf16x8 h; } cv;
                cv.u[0] = pkbf(w0.x, w0.y); cv.u[1] = pkbf(w0.z, w0.w);
                cv.u[2] = pkbf(w1.x, w1.y); cv.u[3] = pkbf(w1.z, w1.w);
                afr[mi][ks] = cv.h;
            }
#pragma unroll
        for (int ks = 0; ks < 2; ++ks)
#pragma unroll
            for (int mi = 0; mi < MI; ++mi)
#pragma unroll
                for (int nf = 0; nf < 4; ++nf)
                    acc[mi][nf] = __builtin_amdgcn_mfma_f32_16x16x32_bf16(
                        afr[mi][ks], bfr[ks][nf], acc[mi][nf], 0, 0, 0);
    }
#pragma unroll
    for (int mi = 0; mi < MI; ++mi)
#pragma unroll
        for (int nf = 0; nf < 4; ++nf)
#pragma unroll
            for (int reg = 0; reg < 4; ++reg) {
                int r = r0 + w * (MI * 16) + mi * 16 + lk * 4 + reg;
                int bcol = nf * 16 + lr;
                float v = acc[mi][nf][reg];
                if (DIRECT) out[r * 64 + bcol] = v + bias[r];
                else atomicAdd(&out[r * 64 + bcol], v);
            }
}

template <int DIRECT, int MI>
__global__ __launch_bounds__(256) void mgemm(
        const float* __restrict__ W, const float* __restrict__ bias,
        const unsigned short* __restrict__ xA, int sA,
        const unsigned short* __restrict__ xB, int sB, int K1,
        int K, int Kc, int splitk, float* __restrict__ out) {
    mgemm_body<DIRECT, MI>(blockIdx.x, W, bias, xA, sA, xB, sB, K1, K, Kc, splitk, out);
}

// ---------------- merged GRU GEMMs: blocks 0..191 Wih (splitk 8), 192..383 Whh (splitk 8) ----------------
__global__ __launch_bounds__(256) void gru2(
        const float* __restrict__ Wih, const float* __restrict__ Whh,
        const unsigned short* __restrict__ gruInB, const unsigned short* __restrict__ xaB512,
        float* __restrict__ giT, float* __restrict__ ghT) {
    const float* W; const unsigned short* x; int s, K1, K, Kc; float* out; int bid;
    if (blockIdx.x < 192) { W = Wih; x = gruInB; s = 2048; K1 = 2048; K = 2048; Kc = 256; out = giT; bid = blockIdx.x; }
    else                  { W = Whh; x = xaB512; s = 1536; K1 = 1024; K = 1024; Kc = 128; out = ghT; bid = blockIdx.x - 192; }
    mgemm_body<0, 2>(bid, W, nullptr, x, s, x, s, K1, K, Kc, 8, out);
}

// ---------------- K2: softmax(a) + sel; stream enc over an L-chunk (16 rows), atomic partials ----------------
__global__ __launch_bounds__(256) void k2_softmax_enc(
        const float* __restrict__ aT, const int* __restrict__ tok, const int* __restrict__ seq,
        const float* __restrict__ pprob, const float* __restrict__ enc,
        float* __restrict__ ap4T, float* __restrict__ gruSelF, float* __restrict__ out3) {
    int b = blockIdx.x, lc = blockIdx.y, t = threadIdx.x;
    __shared__ float red[256];
    __shared__ float w_s[16], sel_s[16];
    float av = (t < LL) ? aT[t * 64 + b] : -1e30f;
    red[t] = av; __syncthreads();
    for (int s = 128; s > 0; s >>= 1) { if (t < s) red[t] = fmaxf(red[t], red[t + s]); __syncthreads(); }
    float m = red[0]; __syncthreads();
    float e = (t < LL) ? fexp(av - m) : 0.f;
    red[t] = e; __syncthreads();
    for (int s = 128; s > 0; s >>= 1) { if (t < s) red[t] += red[t + s]; __syncthreads(); }
    float Z = red[0]; __syncthreads();
    if (t < LL) {
        float wv = e / Z;
        if (lc == 0) out3[b * LL + t] = wv;
        int l0 = lc * 16;
        if (t >= l0 && t < l0 + 16) {
            w_s[t - l0] = wv;
            sel_s[t - l0] = (seq[b * LL + t] == tok[b]) ? pprob[b * LL + t] : 0.f;
        }
    }
    __syncthreads();
    float accA[4] = {0.f,0.f,0.f,0.f}, accS[4] = {0.f,0.f,0.f,0.f};
    const float* encb = enc + (size_t)b * LL * HH + (size_t)lc * 16 * HH;
    for (int l = 0; l < 16; ++l) {
        float wl = w_s[l], sl = sel_s[l];
#pragma unroll
        for (int i = 0; i < 4; ++i) {
            float ev = encb[l * HH + t + i * 256];
            accA[i] += wl * ev;
            accS[i] += sl * truncf(ev);
        }
    }
#pragma unroll
    for (int i = 0; i < 4; ++i) {
        int h = t + i * 256;
        atomicAdd(&ap4T[(h >> 2) * 256 + b * 4 + (h & 3)], accA[i]);
        atomicAdd(&gruSelF[(h >> 2) * 256 + b * 4 + (h & 3)], accS[i]);
    }
}

// ---------------- cvt_ap: ap4T (f32 4T) -> apB[b][k] bf16 ----------------
__global__ void cvt_ap(const float* __restrict__ ap4T, unsigned short* __restrict__ apB) {
    int tid = blockIdx.x * 256 + threadIdx.x;  // 16384
    int b = tid & 63, kq = tid >> 6;
    float4 v = *(const float4*)&ap4T[kq * 256 + b * 4];
    ushort4 o;
    o.x = f2bf(v.x); o.y = f2bf(v.y); o.z = f2bf(v.z); o.w = f2bf(v.w);
    *(ushort4*)&apB[b * 1024 + kq * 4] = o;
}

// ---------------- cvt_gruIn: [relu(gruOutF); gruSelF] -> gruInB[b][0..2048) bf16 ----------------
__global__ void cvt_gruIn(const float* __restrict__ gruOutF, const float* __restrict__ gruSelF,
                          unsigned short* __restrict__ gruInB) {
    int tid = blockIdx.x * 256 + threadIdx.x;  // 32768
    int b = tid & 63, kq = tid >> 6;
    float4 v;
    if (kq < 256) {
        int k = kq * 4;
        v.x = fmaxf(gruOutF[(k + 0) * 64 + b], 0.f);
        v.y = fmaxf(gruOutF[(k + 1) * 64 + b], 0.f);
        v.z = fmaxf(gruOutF[(k + 2) * 64 + b], 0.f);
        v.w = fmaxf(gruOutF[(k + 3) * 64 + b], 0.f);
    } else {
        v = *(const float4*)&gruSelF[(kq - 256) * 256 + b * 4];
    }
    ushort4 o;
    o.x = f2bf(v.x); o.y = f2bf(v.y); o.z = f2bf(v.z); o.w = f2bf(v.w);
    *(ushort4*)&gruInB[b * 2048 + kq * 4] = o;
}

// ---------------- K5: GRU gates -> h_new ----------------
__global__ void k5_gates(const float* __restrict__ giT, const float* __restrict__ ghT,
                         const float* __restrict__ hidden, float* __restrict__ hn4T,
                         unsigned short* __restrict__ hnB, float* __restrict__ out2) {
    int idx = blockIdx.x * 256 + threadIdx.x;   // 65536
    int r = idx >> 6, b = idx & 63;
    float ir = giT[r * 64 + b], iz = giT[(HH + r) * 64 + b], in_ = giT[(2 * HH + r) * 64 + b];
    float hr = ghT[r * 64 + b], hz = ghT[(HH + r) * 64 + b], hn = ghT[(2 * HH + r) * 64 + b];
    float rr = 1.f / (1.f + fexp(-(ir + hr)));
    float zz = 1.f / (1.f + fexp(-(iz + hz)));
    float nn = ftanh(in_ + rr * hn);
    float hprev = hidden[b * HH + r];
    float hnew = (1.f - zz) * nn + zz * hprev;
    hn4T[(r >> 2) * 256 + b * 4 + (r & 3)] = hnew;
    hnB[b * 1024 + r] = f2bf(hnew);
    out2[b * HH + r] = hnew;
}

// ---------------- WOW_F1: WoW GEMM, 64 rows/block x 500 blocks; DOUBLE-BUFFERED LDS W staging
// with raw s_barrier + counted vmcnt (T3/T4 2-phase) + fused f1 partial ----------------
__global__ __launch_bounds__(256) void wow_f1(
        const float* __restrict__ WoW, const float* __restrict__ Wob,
        const unsigned short* __restrict__ hnB, float* __restrict__ sgT,
        float* __restrict__ partMt, float* __restrict__ partSt) {
    __shared__ __align__(16) float Ws[2][64 * 64];   // 2 x 16 KB: 64 rows x 16 chunks(16B)
    __shared__ float pm_s[4 * 64], ps_s[4 * 64];
    int tid = threadIdx.x, w = tid >> 6, lane = tid & 63;
    int lr = lane & 15, lk = lane >> 4;
    int r0 = blockIdx.x * 64;
    int arow = w * 16 + lr;                       // A-fragment row this lane serves
    int sw = arow & 7;                            // read-side XOR key
    f32x4 acc[4];
#pragma unroll
    for (int nf = 0; nf < 4; ++nf) acc[nf] = (f32x4){0.f, 0.f, 0.f, 0.f};

    // stage(buf, kt): 1024 16B chunks, dest linear, source chunk pre-swizzled (ch^(row&7))
    auto stage = [&](int buf, int kt) {
#pragma unroll
        for (int i = 0; i < 4; ++i) {
            int c = i * 256 + tid;
            int row = c >> 4, ch = c & 15;
            int chs = ch ^ (row & 7);
            gload_lds16(WoW + (size_t)(r0 + row) * HH + kt * 64 + chs * 4,
                        (char*)Ws[buf] + (i * 256 + w * 64) * 16);
        }
    };

    stage(0, 0);                                  // 4 gload_lds per wave in flight
    for (int kt = 0; kt < 16; ++kt) {
        int cur = kt & 1;
        // B fragments (hnB 128 KB, L2-hot) -- issued before next-stage so vmcnt(4) covers them
        int kb = kt * 64;
        bf16x8 bfr[2][4];
#pragma unroll
        for (int ks = 0; ks < 2; ++ks)
#pragma unroll
            for (int nf = 0; nf < 4; ++nf)
                bfr[ks][nf] = *(const bf16x8*)(hnB + (nf * 16 + lr) * 1024 + kb + ks * 32 + lk * 8);
        if (kt + 1 < 16) {
            stage(cur ^ 1, kt + 1);               // prefetch next tile (stays in flight)
            asm volatile("s_waitcnt vmcnt(4)" ::: "memory");   // cur tile + bfr retired
        } else {
            asm volatile("s_waitcnt vmcnt(0)" ::: "memory");
        }
        __builtin_amdgcn_s_barrier();             // raw: no implicit vmcnt(0) drain
        __builtin_amdgcn_sched_barrier(0);
        // A fragments from LDS (swizzled chunks) -> cvt to bf16
        bf16x8 afr[2];
#pragma unroll
        for (int ks = 0; ks < 2; ++ks) {
            int c0 = (ks * 8 + lk * 2) ^ sw;
            int c1 = (ks * 8 + lk * 2 + 1) ^ sw;
            float4 w0 = *(const float4*)((const char*)Ws[cur] + (arow * 16 + c0) * 16);
            float4 w1 = *(const float4*)((const char*)Ws[cur] + (arow * 16 + c1) * 16);
            union { u32x4 u; bf16x8 h; } cv;
            cv.u[0] = pkbf(w0.x, w0.y); cv.u[1] = pkbf(w0.z, w0.w);
            cv.u[2] = pkbf(w1.x, w1.y); cv.u[3] = pkbf(w1.z, w1.w);
            afr[ks] = cv.h;
        }
#pragma unroll
        for (int ks = 0; ks < 2; ++ks)
#pragma unroll
            for (int nf = 0; nf < 4; ++nf)
                acc[nf] = __builtin_amdgcn_mfma_f32_16x16x32_bf16(afr[ks], bfr[ks][nf], acc[nf], 0, 0, 0);
        asm volatile("s_waitcnt lgkmcnt(0)" ::: "memory");  // all LDS reads of cur done
        __builtin_amdgcn_sched_barrier(0);
        __builtin_amdgcn_s_barrier();             // protect cur before it is re-staged
    }
    // epilogue: bias, store sgT, fused per-batch online (m,s) partial
#pragma unroll
    for (int nf = 0; nf < 4; ++nf) {
        int bcol = nf * 16 + lr;
        float m = -1e30f, s = 0.f;
#pragma unroll
        for (int reg = 0; reg < 4; ++reg) {
            int r = r0 + w * 16 + lk * 4 + reg;
            float v = acc[nf][reg] + Wob[r];
            sgT[r * 64 + bcol] = v;
            float nm = fmaxf(m, v);
            s = s * fexp(m - nm) + fexp(v - nm);
            m = nm;
        }
#pragma unroll
        for (int d = 16; d <= 32; d <<= 1) {
            float om = __shfl_xor(m, d), os = __shfl_xor(s, d);
            smerge(m, s, om, os);
        }
        if (lk == 0) { pm_s[w * 64 + bcol] = m; ps_s[w * 64 + bcol] = s; }
    }
    __syncthreads();
    if (tid < 64) {
        float m = pm_s[tid], s = ps_s[tid];
        smerge(m, s, pm_s[64 + tid], ps_s[64 + tid]);
        smerge(m, s, pm_s[128 + tid], ps_s[128 + tid]);
        smerge(m, s, pm_s[192 + tid], ps_s[192 + tid]);
        partMt[tid * 512 + blockIdx.x] = m;
        partSt[tid * 512 + blockIdx.x] = s;
    }
}

// ---------------- K7: MFMA bf16 GEMM + fused tanh*h reduce -> sc (128x128, single-buffer, XCD swizzle) ----------------
__global__ __launch_bounds__(256) void k7_mfma(const unsigned short* __restrict__ encB,
        const unsigned short* __restrict__ WcB, const float* __restrict__ Wcb,
        const float* __restrict__ hn4T, float* __restrict__ sc) {
    __shared__ __align__(16) unsigned short As[128 * 64];
    __shared__ __align__(16) unsigned short Bs[128 * 64];
    __shared__ float h_s[128], bias_s[128];
    int tid = threadIdx.x, w = tid >> 6, lane = tid & 63;
    int wm = w >> 1, wn = w & 1;
    int bid = blockIdx.x;
    int swz = (bid & 7) * 64 + (bid >> 3);   // bijective XCD swizzle, 512 = 8*64
    int mt = swz >> 3, nt = swz & 7;
    int m0 = mt * 128, n0 = nt * 128;
    if (tid < 128) {
        int n = n0 + tid;
        bias_s[tid] = Wcb[n];
        h_s[tid] = hn4T[(n >> 2) * 256 + mt * 4 + (n & 3)];
    }
    f32x4 acc[4][4];
#pragma unroll
    for (int mi = 0; mi < 4; ++mi)
#pragma unroll
        for (int ni = 0; ni < 4; ++ni) acc[mi][ni] = (f32x4){0.f, 0.f, 0.f, 0.f};

    for (int kt = 0; kt < 16; ++kt) {
        __syncthreads();
#pragma unroll
        for (int i = 0; i < 4; ++i) {
            int c = i * 256 + tid;
            int row = c >> 3, cc = c & 7;
            int lc2 = cc ^ (row & 7);
            gload_lds16(encB + (size_t)(m0 + row) * HH + kt * 64 + lc2 * 8,
                        (char*)As + (i * 256 + w * 64) * 16);
        }
#pragma unroll
        for (int i = 0; i < 4; ++i) {
            int c = i * 256 + tid;
            int row = c >> 3, cc = c & 7;
            int lc2 = cc ^ (row & 7);
            gload_lds16(WcB + (size_t)(n0 + row) * HH + kt * 64 + lc2 * 8,
                        (char*)Bs + (i * 256 + w * 64) * 16);
        }
        asm volatile("s_waitcnt vmcnt(0)");
        __syncthreads();
#pragma unroll
        for (int ks = 0; ks < 2; ++ks) {
            bf16x8 af[4], bf[4];
#pragma unroll
            for (int mi = 0; mi < 4; ++mi) {
                int rr = wm * 64 + mi * 16 + (lane & 15);
                int lkk = ks * 4 + (lane >> 4);
                af[mi] = *(const bf16x8*)((const char*)As + rr * 128 + ((lkk ^ (rr & 7)) * 16));
            }
#pragma unroll
            for (int ni = 0; ni < 4; ++ni) {
                int rr = wn * 64 + ni * 16 + (lane & 15);
                int lkk = ks * 4 + (lane >> 4);
                bf[ni] = *(const bf16x8*)((const char*)Bs + rr * 128 + ((lkk ^ (rr & 7)) * 16));
            }
#pragma unroll
            for (int mi = 0; mi < 4; ++mi)
#pragma unroll
                for (int ni = 0; ni < 4; ++ni)
                    acc[mi][ni] = __builtin_amdgcn_mfma_f32_16x16x32_bf16(af[mi], bf[ni], acc[mi][ni], 0, 0, 0);
        }
    }
    float rs[16];
#pragma unroll
    for (int z = 0; z < 16; ++z) rs[z] = 0.f;
#pragma unroll
    for (int ni = 0; ni < 4; ++ni) {
        int nl = wn * 64 + ni * 16 + (lane & 15);
        float hv = h_s[nl], bv = bias_s[nl];
#pragma unroll
        for (int mi = 0; mi < 4; ++mi)
#pragma unroll
            for (int reg = 0; reg < 4; ++reg)
                rs[mi * 4 + reg] += ftanh(acc[mi][ni][reg] + bv) * hv;
    }
#pragma unroll
    for (int z = 0; z < 16; ++z) {
        float v = rs[z];
        v += __shfl_xor(v, 1); v += __shfl_xor(v, 2);
        v += __shfl_xor(v, 4); v += __shfl_xor(v, 8);
        rs[z] = v;
    }
    if ((lane & 15) == 0) {
        int g = lane >> 4;
#pragma unroll
        for (int mi = 0; mi < 4; ++mi)
#pragma unroll
            for (int reg = 0; reg < 4; ++reg)
                atomicAdd(&sc[mt * LL + wm * 64 + mi * 16 + g * 4 + reg], rs[mi * 4 + reg]);
    }
}

// ---------------- F1c: tree-combine partials + sc -> M,Z ; write out4 + scatter into out1 ----------------
__global__ __launch_bounds__(256) void f1c_final(const float* __restrict__ partMt,
        const float* __restrict__ partSt, const float* __restrict__ sc,
        const int* __restrict__ seq, float* __restrict__ Mb, float* __restrict__ Zb,
        float* __restrict__ out4, float* __restrict__ out1) {
    int b = blockIdx.x, t = threadIdx.x;
    __shared__ float mred[256], sred[256];
    float m = -1e30f, s = 0.f;
    for (int w = t; w < 500; w += 256)
        smerge(m, s, partMt[b * 512 + w], partSt[b * 512 + w]);
    if (t < 128) smerge(m, s, sc[b * LL + t], 1.0f);
    mred[t] = m; sred[t] = s; __syncthreads();
    for (int st = 128; st > 0; st >>= 1) {
        if (t < st) {
            float mm = mred[t], ss = sred[t];
            smerge(mm, ss, mred[t + st], sred[t + st]);
            mred[t] = mm; sred[t] = ss;
        }
        __syncthreads();
    }
    float M = mred[0], Z = sred[0];
    if (t == 0) { Mb[b] = M; Zb[b] = Z; }
    if (t < 128) {
        float p = fexp(sc[b * LL + t] - M) / Z;
        out4[b * LL + t] = p;
        atomicAdd(&out1[(size_t)b * MAXV + seq[b * LL + t]], p);
    }
}

// ---------------- F2F4: prob_g + scatter-sum, floor, col2, log -> out1 (single pass) ----------------
__global__ void f2f4_final(const float* __restrict__ sgT, const float* __restrict__ Mb,
                           const float* __restrict__ Zb, float* __restrict__ out1) {
    int b = blockIdx.y;
    int v = blockIdx.x * 256 + threadIdx.x;
    if (v >= MAXV) return;
    float val = 0.f;
    if (v < VV) {
        float scat = out1[(size_t)b * MAXV + v];
        val = fexp(sgT[v * 64 + b] - Mb[b]) / Zb[b] + scat;
    }
    if (v == 2 || val == 0.f) val = 1e-9f;
    out1[(size_t)b * MAXV + v] = flog(val);
}

extern "C" void kernel_launch(void* const* d_in, const int* in_sizes, int n_in,
                              void* d_out, int out_size, void* d_ws, size_t ws_size,
                              hipStream_t stream) {
    (void)in_sizes; (void)n_in; (void)out_size; (void)ws_size;
    const int*   tok    = (const int*)  d_in[0];
    const float* hidden = (const float*)d_in[1];
    const float* enc    = (const float*)d_in[2];
    const int*   seq    = (const int*)  d_in[3];
    const float* pprob  = (const float*)d_in[4];
    const float* emb    = (const float*)d_in[5];
    const float* attnW  = (const float*)d_in[6];
    const float* attnb  = (const float*)d_in[7];
    const float* combW  = (const float*)d_in[8];
    const float* combb  = (const float*)d_in[9];
    const float* Wih    = (const float*)d_in[10];
    const float* Whh    = (const float*)d_in[11];
    const float* bih    = (const float*)d_in[12];
    const float* bhh    = (const float*)d_in[13];
    const float* WoW    = (const float*)d_in[14];
    const float* Wob    = (const float*)d_in[15];
    const float* WcW    = (const float*)d_in[16];
    const float* Wcb    = (const float*)d_in[17];

    float* out1 = (float*)d_out;
    float* out2 = out1 + (size_t)BB * MAXV;
    float* out3 = out2 + BB * HH;
    float* out4 = out3 + BB * LL;

    float* ws      = (float*)d_ws;
    float* aT      = ws;                    // 8192
    float* ap4T    = ws + 8192;             // 65536  (zero region start)
    float* gruSelF = ws + 73728;            // 65536
    float* sc      = ws + 139264;           // 8192   (zero region len 139264)
    float* gruOutF = ws + 147456;           // 65536
    float* giT     = ws + 212992;           // 196608
    float* ghT     = ws + 409600;           // 196608
    float* hn4T    = ws + 606208;           // 65536
    float* sgT     = ws + 671744;           // 2048000
    float* partMt  = ws + 2719744;          // 32768 (64 x 512)
    float* partSt  = ws + 2752512;          // 32768
    float* Mb      = ws + 2785280;          // 64
    float* Zb      = ws + 2785344;          // 64
    unsigned short* encB = (unsigned short*)(ws + 2785408);   // 8388608 bf16 -> f 6979712
    unsigned short* WcB  = encB + 8388608;                    // 1048576 bf16 -> f 7504000
    unsigned short* hnB  = (unsigned short*)(ws + 7504000);   // 65536 bf16 -> f 7536768
    // transient bf16 x-buffers inside sgT region (consumed before sgT is written)
    unsigned short* xaB    = (unsigned short*)sgT;            // 98304 bf16 (f 671744..720896)
    unsigned short* apB    = (unsigned short*)(ws + 720896);  // 65536 bf16 (..753664)
    unsigned short* gruInB = (unsigned short*)(ws + 753664);  // 131072 bf16 (..819200)

    setup2       <<<13968, 256, 0, stream>>>(enc, encB, WcW, WcB, tok, hidden, emb, xaB,
                                             attnb, combb, bih, bhh,
                                             aT, gruOutF, giT, ghT, ap4T, out1);
    mgemm<0,2>   <<<12, 256, 0, stream>>>(attnW, nullptr, xaB, 1536, xaB, 1536, 1536, 1536, 128, 12, aT);
    k2_softmax_enc<<<dim3(64, 8), 256, 0, stream>>>(aT, tok, seq, pprob, enc, ap4T, gruSelF, out3);
    cvt_ap       <<<64, 256, 0, stream>>>(ap4T, apB);
    mgemm<0,2>   <<<96, 256, 0, stream>>>(combW, nullptr, xaB, 1536, apB, 1024, 512, 1536, 128, 12, gruOutF);
    cvt_gruIn    <<<128, 256, 0, stream>>>(gruOutF, gruSelF, gruInB);
    gru2         <<<384, 256, 0, stream>>>(Wih, Whh, gruInB, xaB + 512, giT, ghT);
    k5_gates     <<<256, 256, 0, stream>>>(giT, ghT, hidden, hn4T, hnB, out2);
    wow_f1       <<<500, 256, 0, stream>>>(WoW, Wob, hnB, sgT, partMt, partSt);
    k7_mfma      <<<512, 256, 0, stream>>>(encB, WcB, Wcb, hn4T, sc);
    f1c_final    <<<64, 256, 0, stream>>>(partMt, partSt, sc, seq, Mb, Zb, out4, out1);
    f2f4_final   <<<dim3(129, 64), 256, 0, stream>>>(sgT, Mb, Zb, out1);
}

// Round 18
// 166.687 us; speedup vs baseline: 1.0207x; 1.0048x over previous
//
#include <hip/hip_runtime.h>
#include <math.h>

#define BB 64
#define LL 128
#define HH 1024
#define EE 512
#define VV 32000
#define MAXV 33000

typedef float f32x4 __attribute__((ext_vector_type(4)));
typedef short bf16x8 __attribute__((ext_vector_type(8)));
typedef unsigned u32x4 __attribute__((ext_vector_type(4)));

__device__ __forceinline__ void gload_lds16(const void* g, void* l) {
    __builtin_amdgcn_global_load_lds((const __attribute__((address_space(1))) void*)g,
                                     (__attribute__((address_space(3))) void*)l, 16, 0, 0);
}

__device__ __forceinline__ unsigned short f2bf(float f) {
    unsigned u = __float_as_uint(f);
    return (unsigned short)((u + 0x7fffu + ((u >> 16) & 1u)) >> 16);
}

__device__ __forceinline__ unsigned pkbf(float a, float b) {
    unsigned r;
    asm("v_cvt_pk_bf16_f32 %0, %1, %2" : "=v"(r) : "v"(a), "v"(b));
    return r;
}

// fast exp/log/tanh (v_exp_f32 / v_log_f32 paths), err ~1e-6 rel
__device__ __forceinline__ float fexp(float x) { return __expf(x); }
__device__ __forceinline__ float flog(float x) { return __logf(x); }
__device__ __forceinline__ float ftanh(float x) { return 1.f - 2.f / (1.f + __expf(2.f * x)); }

__device__ __forceinline__ void smerge(float& m, float& s, float m2, float s2) {
    float nm = fmaxf(m, m2);
    s = s * fexp(m - nm) + s2 * fexp(m2 - nm);
    m = nm;
}

// ---------------- SETUP2: cvt enc->bf16 | cvt WcW->bf16 | build xaB | bias-preinit | zeros | zero out1 ----------------
#define N_ENC4 2097152
__global__ void setup2(const float* __restrict__ enc, unsigned short* __restrict__ encB,
                       const float* __restrict__ WcW, unsigned short* __restrict__ WcB,
                       const int* __restrict__ tok, const float* __restrict__ hidden,
                       const float* __restrict__ emb, unsigned short* __restrict__ xaB,
                       const float* __restrict__ attnb, const float* __restrict__ combb,
                       const float* __restrict__ bih, const float* __restrict__ bhh,
                       float* __restrict__ aT, float* __restrict__ gruOutF,
                       float* __restrict__ giT, float* __restrict__ ghT,
                       float* __restrict__ zeros, float* __restrict__ out1) {
    int idx = blockIdx.x * 256 + threadIdx.x;   // 3575808 total
    if (idx < N_ENC4) {
        float4 v = ((const float4*)enc)[idx];
        ushort4 o;
        o.x = f2bf(v.x); o.y = f2bf(v.y); o.z = f2bf(v.z); o.w = f2bf(v.w);
        ((ushort4*)encB)[idx] = o;
        return;
    }
    idx -= N_ENC4;
    if (idx < 262144) {
        float4 v = ((const float4*)WcW)[idx];
        ushort4 o;
        o.x = f2bf(v.x); o.y = f2bf(v.y); o.z = f2bf(v.z); o.w = f2bf(v.w);
        ((ushort4*)WcB)[idx] = o;
        return;
    }
    idx -= 262144;
    if (idx < 98304) {
        int b = idx / 1536, k = idx % 1536;
        float v = (k < EE) ? emb[tok[b] * EE + k] : hidden[b * HH + (k - EE)];
        xaB[b * 1536 + k] = f2bf(v);
        return;
    }
    idx -= 98304;
    if (idx < 8192) { aT[idx] = attnb[idx >> 6]; return; }
    idx -= 8192;
    if (idx < 65536) { gruOutF[idx] = combb[idx >> 6]; return; }
    idx -= 65536;
    if (idx < 196608) { giT[idx] = bih[idx >> 6]; return; }
    idx -= 196608;
    if (idx < 196608) { ghT[idx] = bhh[idx >> 6]; return; }
    idx -= 196608;
    if (idx < 139264) { zeros[idx] = 0.f; return; }
    idx -= 139264;
    int b = idx / 8000, q = idx % 8000;
    ((float4*)(out1 + (size_t)b * MAXV))[q] = (float4){0.f, 0.f, 0.f, 0.f};
}

// ---------------- mgemm body: out[r][b] = sum_k W[r][k] * x[b][k]  (x bf16, W f32->bf16 in-reg) ----------------
template <int DIRECT, int MI>
__device__ __forceinline__ void mgemm_body(int bid,
        const float* __restrict__ W, const float* __restrict__ bias,
        const unsigned short* __restrict__ xA, int sA,
        const unsigned short* __restrict__ xB, int sB, int K1,
        int K, int Kc, int splitk, float* __restrict__ out) {
    int tid = threadIdx.x, w = tid >> 6, lane = tid & 63;
    int rb = bid / splitk, kseg = bid - rb * splitk;
    int r0 = rb * (MI * 64), kb0 = kseg * Kc;
    int lr = lane & 15, lk = lane >> 4;
    int nt = Kc >> 6;
    f32x4 acc[MI][4];
#pragma unroll
    for (int mi = 0; mi < MI; ++mi)
#pragma unroll
        for (int nf = 0; nf < 4; ++nf) acc[mi][nf] = (f32x4){0.f, 0.f, 0.f, 0.f};
    const float* Wr[MI];
#pragma unroll
    for (int mi = 0; mi < MI; ++mi)
        Wr[mi] = W + (size_t)(r0 + w * (MI * 16) + mi * 16 + lr) * K;

    for (int t = 0; t < nt; ++t) {
        int kb = kb0 + t * 64;
        bf16x8 bfr[2][4];
#pragma unroll
        for (int ks = 0; ks < 2; ++ks)
#pragma unroll
            for (int nf = 0; nf < 4; ++nf) {
                int bcol = nf * 16 + lr;
                int kg = kb + ks * 32 + lk * 8;
                const unsigned short* xp = (kg < K1) ? (xA + bcol * sA + kg)
                                                     : (xB + bcol * sB + (kg - K1));
                bfr[ks][nf] = *(const bf16x8*)xp;
            }
        bf16x8 afr[MI][2];
#pragma unroll
        for (int mi = 0; mi < MI; ++mi)
#pragma unroll
            for (int ks = 0; ks < 2; ++ks) {
                const float* wp = Wr[mi] + kb + ks * 32 + lk * 8;
                float4 w0 = *(const float4*)wp;
                float4 w1 = *(const float4*)(wp + 4);
                union { u32x4 u; bf16x8 h; } cv;
                cv.u[0] = pkbf(w0.x, w0.y); cv.u[1] = pkbf(w0.z, w0.w);
                cv.u[2] = pkbf(w1.x, w1.y); cv.u[3] = pkbf(w1.z, w1.w);
                afr[mi][ks] = cv.h;
            }
#pragma unroll
        for (int ks = 0; ks < 2; ++ks)
#pragma unroll
            for (int mi = 0; mi < MI; ++mi)
#pragma unroll
                for (int nf = 0; nf < 4; ++nf)
                    acc[mi][nf] = __builtin_amdgcn_mfma_f32_16x16x32_bf16(
                        afr[mi][ks], bfr[ks][nf], acc[mi][nf], 0, 0, 0);
    }
#pragma unroll
    for (int mi = 0; mi < MI; ++mi)
#pragma unroll
        for (int nf = 0; nf < 4; ++nf)
#pragma unroll
            for (int reg = 0; reg < 4; ++reg) {
                int r = r0 + w * (MI * 16) + mi * 16 + lk * 4 + reg;
                int bcol = nf * 16 + lr;
                float v = acc[mi][nf][reg];
                if (DIRECT) out[r * 64 + bcol] = v + bias[r];
                else atomicAdd(&out[r * 64 + bcol], v);
            }
}

template <int DIRECT, int MI>
__global__ __launch_bounds__(256) void mgemm(
        const float* __restrict__ W, const float* __restrict__ bias,
        const unsigned short* __restrict__ xA, int sA,
        const unsigned short* __restrict__ xB, int sB, int K1,
        int K, int Kc, int splitk, float* __restrict__ out) {
    mgemm_body<DIRECT, MI>(blockIdx.x, W, bias, xA, sA, xB, sB, K1, K, Kc, splitk, out);
}

// ---------------- merged GRU GEMMs: blocks 0..191 Wih (splitk 8), 192..383 Whh (splitk 8) ----------------
__global__ __launch_bounds__(256) void gru2(
        const float* __restrict__ Wih, const float* __restrict__ Whh,
        const unsigned short* __restrict__ gruInB, const unsigned short* __restrict__ xaB512,
        float* __restrict__ giT, float* __restrict__ ghT) {
    const float* W; const unsigned short* x; int s, K1, K, Kc; float* out; int bid;
    if (blockIdx.x < 192) { W = Wih; x = gruInB; s = 2048; K1 = 2048; K = 2048; Kc = 256; out = giT; bid = blockIdx.x; }
    else                  { W = Whh; x = xaB512; s = 1536; K1 = 1024; K = 1024; Kc = 128; out = ghT; bid = blockIdx.x - 192; }
    mgemm_body<0, 2>(bid, W, nullptr, x, s, x, s, K1, K, Kc, 8, out);
}

// ---------------- K2: softmax(a) + sel; stream enc over an L-chunk (16 rows), atomic partials ----------------
__global__ __launch_bounds__(256) void k2_softmax_enc(
        const float* __restrict__ aT, const int* __restrict__ tok, const int* __restrict__ seq,
        const float* __restrict__ pprob, const float* __restrict__ enc,
        float* __restrict__ ap4T, float* __restrict__ gruSelF, float* __restrict__ out3) {
    int b = blockIdx.x, lc = blockIdx.y, t = threadIdx.x;
    __shared__ float red[256];
    __shared__ float w_s[16], sel_s[16];
    float av = (t < LL) ? aT[t * 64 + b] : -1e30f;
    red[t] = av; __syncthreads();
    for (int s = 128; s > 0; s >>= 1) { if (t < s) red[t] = fmaxf(red[t], red[t + s]); __syncthreads(); }
    float m = red[0]; __syncthreads();
    float e = (t < LL) ? fexp(av - m) : 0.f;
    red[t] = e; __syncthreads();
    for (int s = 128; s > 0; s >>= 1) { if (t < s) red[t] += red[t + s]; __syncthreads(); }
    float Z = red[0]; __syncthreads();
    if (t < LL) {
        float wv = e / Z;
        if (lc == 0) out3[b * LL + t] = wv;
        int l0 = lc * 16;
        if (t >= l0 && t < l0 + 16) {
            w_s[t - l0] = wv;
            sel_s[t - l0] = (seq[b * LL + t] == tok[b]) ? pprob[b * LL + t] : 0.f;
        }
    }
    __syncthreads();
    float accA[4] = {0.f,0.f,0.f,0.f}, accS[4] = {0.f,0.f,0.f,0.f};
    const float* encb = enc + (size_t)b * LL * HH + (size_t)lc * 16 * HH;
    for (int l = 0; l < 16; ++l) {
        float wl = w_s[l], sl = sel_s[l];
#pragma unroll
        for (int i = 0; i < 4; ++i) {
            float ev = encb[l * HH + t + i * 256];
            accA[i] += wl * ev;
            accS[i] += sl * truncf(ev);
        }
    }
#pragma unroll
    for (int i = 0; i < 4; ++i) {
        int h = t + i * 256;
        atomicAdd(&ap4T[(h >> 2) * 256 + b * 4 + (h & 3)], accA[i]);
        atomicAdd(&gruSelF[(h >> 2) * 256 + b * 4 + (h & 3)], accS[i]);
    }
}

// ---------------- cvt_ap: ap4T (f32 4T) -> apB[b][k] bf16 ----------------
__global__ void cvt_ap(const float* __restrict__ ap4T, unsigned short* __restrict__ apB) {
    int tid = blockIdx.x * 256 + threadIdx.x;  // 16384
    int b = tid & 63, kq = tid >> 6;
    float4 v = *(const float4*)&ap4T[kq * 256 + b * 4];
    ushort4 o;
    o.x = f2bf(v.x); o.y = f2bf(v.y); o.z = f2bf(v.z); o.w = f2bf(v.w);
    *(ushort4*)&apB[b * 1024 + kq * 4] = o;
}

// ---------------- cvt_gruIn: [relu(gruOutF); gruSelF] -> gruInB[b][0..2048) bf16 ----------------
__global__ void cvt_gruIn(const float* __restrict__ gruOutF, const float* __restrict__ gruSelF,
                          unsigned short* __restrict__ gruInB) {
    int tid = blockIdx.x * 256 + threadIdx.x;  // 32768
    int b = tid & 63, kq = tid >> 6;
    float4 v;
    if (kq < 256) {
        int k = kq * 4;
        v.x = fmaxf(gruOutF[(k + 0) * 64 + b], 0.f);
        v.y = fmaxf(gruOutF[(k + 1) * 64 + b], 0.f);
        v.z = fmaxf(gruOutF[(k + 2) * 64 + b], 0.f);
        v.w = fmaxf(gruOutF[(k + 3) * 64 + b], 0.f);
    } else {
        v = *(const float4*)&gruSelF[(kq - 256) * 256 + b * 4];
    }
    ushort4 o;
    o.x = f2bf(v.x); o.y = f2bf(v.y); o.z = f2bf(v.z); o.w = f2bf(v.w);
    *(ushort4*)&gruInB[b * 2048 + kq * 4] = o;
}

// ---------------- K5: GRU gates -> h_new ----------------
__global__ void k5_gates(const float* __restrict__ giT, const float* __restrict__ ghT,
                         const float* __restrict__ hidden, float* __restrict__ hn4T,
                         unsigned short* __restrict__ hnB, float* __restrict__ out2) {
    int idx = blockIdx.x * 256 + threadIdx.x;   // 65536
    int r = idx >> 6, b = idx & 63;
    float ir = giT[r * 64 + b], iz = giT[(HH + r) * 64 + b], in_ = giT[(2 * HH + r) * 64 + b];
    float hr = ghT[r * 64 + b], hz = ghT[(HH + r) * 64 + b], hn = ghT[(2 * HH + r) * 64 + b];
    float rr = 1.f / (1.f + fexp(-(ir + hr)));
    float zz = 1.f / (1.f + fexp(-(iz + hz)));
    float nn = ftanh(in_ + rr * hn);
    float hprev = hidden[b * HH + r];
    float hnew = (1.f - zz) * nn + zz * hprev;
    hn4T[(r >> 2) * 256 + b * 4 + (r & 3)] = hnew;
    hnB[b * 1024 + r] = f2bf(hnew);
    out2[b * HH + r] = hnew;
}

// ---------------- WOW_F1: WoW GEMM, 64 rows/block x 500 blocks; BK=128 LDS-staged W
// (contiguous, XOR-pre-swizzled source); 8 barrier-phases instead of 16; fused f1 partial ----------------
__global__ __launch_bounds__(256) void wow_f1(
        const float* __restrict__ WoW, const float* __restrict__ Wob,
        const unsigned short* __restrict__ hnB, float* __restrict__ sgT,
        float* __restrict__ partMt, float* __restrict__ partSt) {
    __shared__ __align__(16) float Ws[64 * 128];  // 32 KB: 64 rows x 32 chunks(16B)
    __shared__ float pm_s[4 * 64], ps_s[4 * 64];
    int tid = threadIdx.x, w = tid >> 6, lane = tid & 63;
    int lr = lane & 15, lk = lane >> 4;
    int r0 = blockIdx.x * 64;
    int arow = w * 16 + lr;                       // A-fragment row this lane serves
    int sw = arow & 7;                            // read-side XOR key
    f32x4 acc[4];
#pragma unroll
    for (int nf = 0; nf < 4; ++nf) acc[nf] = (f32x4){0.f, 0.f, 0.f, 0.f};

    for (int kt = 0; kt < 8; ++kt) {              // BK=128: 8 phases
        __syncthreads();
        // stage W tile: 2048 16B chunks (64 rows x 32); dest linear, src chunk pre-swizzled
#pragma unroll
        for (int i = 0; i < 8; ++i) {
            int c = i * 256 + tid;
            int row = c >> 5, ch = c & 31;
            int chs = ch ^ (row & 7);
            gload_lds16(WoW + (size_t)(r0 + row) * HH + kt * 128 + chs * 4,
                        (char*)Ws + (i * 256 + w * 64) * 16);
        }
        // B fragments (hnB 128 KB, L2-hot) while staging is in flight
        int kb = kt * 128;
        bf16x8 bfr[4][4];
#pragma unroll
        for (int ks = 0; ks < 4; ++ks)
#pragma unroll
            for (int nf = 0; nf < 4; ++nf)
                bfr[ks][nf] = *(const bf16x8*)(hnB + (nf * 16 + lr) * 1024 + kb + ks * 32 + lk * 8);
        asm volatile("s_waitcnt vmcnt(0)");
        __syncthreads();
        // A fragments from LDS (swizzled chunks) -> cvt to bf16; 4 k-slices
#pragma unroll
        for (int ks = 0; ks < 4; ++ks) {
            int c0 = (ks * 8 + lk * 2) ^ sw;
            int c1 = (ks * 8 + lk * 2 + 1) ^ sw;
            float4 w0 = *(const float4*)((const char*)Ws + (arow * 32 + c0) * 16);
            float4 w1 = *(const float4*)((const char*)Ws + (arow * 32 + c1) * 16);
            union { u32x4 u; bf16x8 h; } cv;
            cv.u[0] = pkbf(w0.x, w0.y); cv.u[1] = pkbf(w0.z, w0.w);
            cv.u[2] = pkbf(w1.x, w1.y); cv.u[3] = pkbf(w1.z, w1.w);
#pragma unroll
            for (int nf = 0; nf < 4; ++nf)
                acc[nf] = __builtin_amdgcn_mfma_f32_16x16x32_bf16(cv.h, bfr[ks][nf], acc[nf], 0, 0, 0);
        }
    }
    // epilogue: bias, store sgT, fused per-batch online (m,s) partial
#pragma unroll
    for (int nf = 0; nf < 4; ++nf) {
        int bcol = nf * 16 + lr;
        float m = -1e30f, s = 0.f;
#pragma unroll
        for (int reg = 0; reg < 4; ++reg) {
            int r = r0 + w * 16 + lk * 4 + reg;
            float v = acc[nf][reg] + Wob[r];
            sgT[r * 64 + bcol] = v;
            float nm = fmaxf(m, v);
            s = s * fexp(m - nm) + fexp(v - nm);
            m = nm;
        }
#pragma unroll
        for (int d = 16; d <= 32; d <<= 1) {
            float om = __shfl_xor(m, d), os = __shfl_xor(s, d);
            smerge(m, s, om, os);
        }
        if (lk == 0) { pm_s[w * 64 + bcol] = m; ps_s[w * 64 + bcol] = s; }
    }
    __syncthreads();
    if (tid < 64) {
        float m = pm_s[tid], s = ps_s[tid];
        smerge(m, s, pm_s[64 + tid], ps_s[64 + tid]);
        smerge(m, s, pm_s[128 + tid], ps_s[128 + tid]);
        smerge(m, s, pm_s[192 + tid], ps_s[192 + tid]);
        partMt[tid * 512 + blockIdx.x] = m;
        partSt[tid * 512 + blockIdx.x] = s;
    }
}

// ---------------- K7: MFMA bf16 GEMM + fused tanh*h reduce -> sc; BK=128 (8 phases), XCD swizzle ----------------
__global__ __launch_bounds__(256) void k7_mfma(const unsigned short* __restrict__ encB,
        const unsigned short* __restrict__ WcB, const float* __restrict__ Wcb,
        const float* __restrict__ hn4T, float* __restrict__ sc) {
    __shared__ __align__(16) unsigned short As[128 * 128];   // 32 KB
    __shared__ __align__(16) unsigned short Bs[128 * 128];   // 32 KB
    __shared__ float h_s[128], bias_s[128];
    int tid = threadIdx.x, w = tid >> 6, lane = tid & 63;
    int wm = w >> 1, wn = w & 1;
    int bid = blockIdx.x;
    int swz = (bid & 7) * 64 + (bid >> 3);   // bijective XCD swizzle, 512 = 8*64
    int mt = swz >> 3, nt = swz & 7;
    int m0 = mt * 128, n0 = nt * 128;
    if (tid < 128) {
        int n = n0 + tid;
        bias_s[tid] = Wcb[n];
        h_s[tid] = hn4T[(n >> 2) * 256 + mt * 4 + (n & 3)];
    }
    f32x4 acc[4][4];
#pragma unroll
    for (int mi = 0; mi < 4; ++mi)
#pragma unroll
        for (int ni = 0; ni < 4; ++ni) acc[mi][ni] = (f32x4){0.f, 0.f, 0.f, 0.f};

    for (int kt = 0; kt < 8; ++kt) {             // BK=128: 8 phases
        __syncthreads();
        // A tile: 2048 16B chunks (128 rows x 16 chunks of 8 bf16)
#pragma unroll
        for (int i = 0; i < 8; ++i) {
            int c = i * 256 + tid;
            int row = c >> 4, cc = c & 15;
            int lc2 = cc ^ (row & 7);
            gload_lds16(encB + (size_t)(m0 + row) * HH + kt * 128 + lc2 * 8,
                        (char*)As + (i * 256 + w * 64) * 16);
        }
#pragma unroll
        for (int i = 0; i < 8; ++i) {
            int c = i * 256 + tid;
            int row = c >> 4, cc = c & 15;
            int lc2 = cc ^ (row & 7);
            gload_lds16(WcB + (size_t)(n0 + row) * HH + kt * 128 + lc2 * 8,
                        (char*)Bs + (i * 256 + w * 64) * 16);
        }
        asm volatile("s_waitcnt vmcnt(0)");
        __syncthreads();
#pragma unroll
        for (int ks = 0; ks < 4; ++ks) {
            bf16x8 af[4], bf[4];
#pragma unroll
            for (int mi = 0; mi < 4; ++mi) {
                int rr = wm * 64 + mi * 16 + (lane & 15);
                int lkk = ks * 4 + (lane >> 4);
                af[mi] = *(const bf16x8*)((const char*)As + rr * 256 + ((lkk ^ (rr & 7)) * 16));
            }
#pragma unroll
            for (int ni = 0; ni < 4; ++ni) {
                int rr = wn * 64 + ni * 16 + (lane & 15);
                int lkk = ks * 4 + (lane >> 4);
                bf[ni] = *(const bf16x8*)((const char*)Bs + rr * 256 + ((lkk ^ (rr & 7)) * 16));
            }
#pragma unroll
            for (int mi = 0; mi < 4; ++mi)
#pragma unroll
                for (int ni = 0; ni < 4; ++ni)
                    acc[mi][ni] = __builtin_amdgcn_mfma_f32_16x16x32_bf16(af[mi], bf[ni], acc[mi][ni], 0, 0, 0);
        }
    }
    float rs[16];
#pragma unroll
    for (int z = 0; z < 16; ++z) rs[z] = 0.f;
#pragma unroll
    for (int ni = 0; ni < 4; ++ni) {
        int nl = wn * 64 + ni * 16 + (lane & 15);
        float hv = h_s[nl], bv = bias_s[nl];
#pragma unroll
        for (int mi = 0; mi < 4; ++mi)
#pragma unroll
            for (int reg = 0; reg < 4; ++reg)
                rs[mi * 4 + reg] += ftanh(acc[mi][ni][reg] + bv) * hv;
    }
#pragma unroll
    for (int z = 0; z < 16; ++z) {
        float v = rs[z];
        v += __shfl_xor(v, 1); v += __shfl_xor(v, 2);
        v += __shfl_xor(v, 4); v += __shfl_xor(v, 8);
        rs[z] = v;
    }
    if ((lane & 15) == 0) {
        int g = lane >> 4;
#pragma unroll
        for (int mi = 0; mi < 4; ++mi)
#pragma unroll
            for (int reg = 0; reg < 4; ++reg)
                atomicAdd(&sc[mt * LL + wm * 64 + mi * 16 + g * 4 + reg], rs[mi * 4 + reg]);
    }
}

// ---------------- F1c: tree-combine partials + sc -> M,Z ; write out4 + scatter into out1 ----------------
__global__ __launch_bounds__(256) void f1c_final(const float* __restrict__ partMt,
        const float* __restrict__ partSt, const float* __restrict__ sc,
        const int* __restrict__ seq, float* __restrict__ Mb, float* __restrict__ Zb,
        float* __restrict__ out4, float* __restrict__ out1) {
    int b = blockIdx.x, t = threadIdx.x;
    __shared__ float mred[256], sred[256];
    float m = -1e30f, s = 0.f;
    for (int w = t; w < 500; w += 256)
        smerge(m, s, partMt[b * 512 + w], partSt[b * 512 + w]);
    if (t < 128) smerge(m, s, sc[b * LL + t], 1.0f);
    mred[t] = m; sred[t] = s; __syncthreads();
    for (int st = 128; st > 0; st >>= 1) {
        if (t < st) {
            float mm = mred[t], ss = sred[t];
            smerge(mm, ss, mred[t + st], sred[t + st]);
            mred[t] = mm; sred[t] = ss;
        }
        __syncthreads();
    }
    float M = mred[0], Z = sred[0];
    if (t == 0) { Mb[b] = M; Zb[b] = Z; }
    if (t < 128) {
        float p = fexp(sc[b * LL + t] - M) / Z;
        out4[b * LL + t] = p;
        atomicAdd(&out1[(size_t)b * MAXV + seq[b * LL + t]], p);
    }
}

// ---------------- F2F4: prob_g + scatter-sum, floor, col2, log -> out1 (single pass) ----------------
__global__ void f2f4_final(const float* __restrict__ sgT, const float* __restrict__ Mb,
                           const float* __restrict__ Zb, float* __restrict__ out1) {
    int b = blockIdx.y;
    int v = blockIdx.x * 256 + threadIdx.x;
    if (v >= MAXV) return;
    float val = 0.f;
    if (v < VV) {
        float scat = out1[(size_t)b * MAXV + v];
        val = fexp(sgT[v * 64 + b] - Mb[b]) / Zb[b] + scat;
    }
    if (v == 2 || val == 0.f) val = 1e-9f;
    out1[(size_t)b * MAXV + v] = flog(val);
}

extern "C" void kernel_launch(void* const* d_in, const int* in_sizes, int n_in,
                              void* d_out, int out_size, void* d_ws, size_t ws_size,
                              hipStream_t stream) {
    (void)in_sizes; (void)n_in; (void)out_size; (void)ws_size;
    const int*   tok    = (const int*)  d_in[0];
    const float* hidden = (const float*)d_in[1];
    const float* enc    = (const float*)d_in[2];
    const int*   seq    = (const int*)  d_in[3];
    const float* pprob  = (const float*)d_in[4];
    const float* emb    = (const float*)d_in[5];
    const float* attnW  = (const float*)d_in[6];
    const float* attnb  = (const float*)d_in[7];
    const float* combW  = (const float*)d_in[8];
    const float* combb  = (const float*)d_in[9];
    const float* Wih    = (const float*)d_in[10];
    const float* Whh    = (const float*)d_in[11];
    const float* bih    = (const float*)d_in[12];
    const float* bhh    = (const float*)d_in[13];
    const float* WoW    = (const float*)d_in[14];
    const float* Wob    = (const float*)d_in[15];
    const float* WcW    = (const float*)d_in[16];
    const float* Wcb    = (const float*)d_in[17];

    float* out1 = (float*)d_out;
    float* out2 = out1 + (size_t)BB * MAXV;
    float* out3 = out2 + BB * HH;
    float* out4 = out3 + BB * LL;

    float* ws      = (float*)d_ws;
    float* aT      = ws;                    // 8192
    float* ap4T    = ws + 8192;             // 65536  (zero region start)
    float* gruSelF = ws + 73728;            // 65536
    float* sc      = ws + 139264;           // 8192   (zero region len 139264)
    float* gruOutF = ws + 147456;           // 65536
    float* giT     = ws + 212992;           // 196608
    float* ghT     = ws + 409600;           // 196608
    float* hn4T    = ws + 606208;           // 65536
    float* sgT     = ws + 671744;           // 2048000
    float* partMt  = ws + 2719744;          // 32768 (64 x 512)
    float* partSt  = ws + 2752512;          // 32768
    float* Mb      = ws + 2785280;          // 64
    float* Zb      = ws + 2785344;          // 64
    unsigned short* encB = (unsigned short*)(ws + 2785408);   // 8388608 bf16 -> f 6979712
    unsigned short* WcB  = encB + 8388608;                    // 1048576 bf16 -> f 7504000
    unsigned short* hnB  = (unsigned short*)(ws + 7504000);   // 65536 bf16 -> f 7536768
    // transient bf16 x-buffers inside sgT region (consumed before sgT is written)
    unsigned short* xaB    = (unsigned short*)sgT;            // 98304 bf16 (f 671744..720896)
    unsigned short* apB    = (unsigned short*)(ws + 720896);  // 65536 bf16 (..753664)
    unsigned short* gruInB = (unsigned short*)(ws + 753664);  // 131072 bf16 (..819200)

    setup2       <<<13968, 256, 0, stream>>>(enc, encB, WcW, WcB, tok, hidden, emb, xaB,
                                             attnb, combb, bih, bhh,
                                             aT, gruOutF, giT, ghT, ap4T, out1);
    mgemm<0,2>   <<<12, 256, 0, stream>>>(attnW, nullptr, xaB, 1536, xaB, 1536, 1536, 1536, 128, 12, aT);
    k2_softmax_enc<<<dim3(64, 8), 256, 0, stream>>>(aT, tok, seq, pprob, enc, ap4T, gruSelF, out3);
    cvt_ap       <<<64, 256, 0, stream>>>(ap4T, apB);
    mgemm<0,2>   <<<96, 256, 0, stream>>>(combW, nullptr, xaB, 1536, apB, 1024, 512, 1536, 128, 12, gruOutF);
    cvt_gruIn    <<<128, 256, 0, stream>>>(gruOutF, gruSelF, gruInB);
    gru2         <<<384, 256, 0, stream>>>(Wih, Whh, gruInB, xaB + 512, giT, ghT);
    k5_gates     <<<256, 256, 0, stream>>>(giT, ghT, hidden, hn4T, hnB, out2);
    wow_f1       <<<500, 256, 0, stream>>>(WoW, Wob, hnB, sgT, partMt, partSt);
    k7_mfma      <<<512, 256, 0, stream>>>(encB, WcB, Wcb, hn4T, sc);
    f1c_final    <<<64, 256, 0, stream>>>(partMt, partSt, sc, seq, Mb, Zb, out4, out1);
    f2f4_final   <<<dim3(129, 64), 256, 0, stream>>>(sgT, Mb, Zb, out1);
}

// Round 19
// 163.723 us; speedup vs baseline: 1.0391x; 1.0181x over previous
//
#include <hip/hip_runtime.h>
#include <math.h>

#define BB 64
#define LL 128
#define HH 1024
#define EE 512
#define VV 32000
#define MAXV 33000

typedef float f32x4 __attribute__((ext_vector_type(4)));
typedef short bf16x8 __attribute__((ext_vector_type(8)));
typedef unsigned u32x4 __attribute__((ext_vector_type(4)));

__device__ __forceinline__ void gload_lds16(const void* g, void* l) {
    __builtin_amdgcn_global_load_lds((const __attribute__((address_space(1))) void*)g,
                                     (__attribute__((address_space(3))) void*)l, 16, 0, 0);
}

__device__ __forceinline__ unsigned short f2bf(float f) {
    unsigned u = __float_as_uint(f);
    return (unsigned short)((u + 0x7fffu + ((u >> 16) & 1u)) >> 16);
}

__device__ __forceinline__ unsigned pkbf(float a, float b) {
    unsigned r;
    asm("v_cvt_pk_bf16_f32 %0, %1, %2" : "=v"(r) : "v"(a), "v"(b));
    return r;
}

// fast exp/log/tanh (v_exp_f32 / v_log_f32 paths), err ~1e-6 rel
__device__ __forceinline__ float fexp(float x) { return __expf(x); }
__device__ __forceinline__ float flog(float x) { return __logf(x); }
__device__ __forceinline__ float ftanh(float x) { return 1.f - 2.f / (1.f + __expf(2.f * x)); }

__device__ __forceinline__ void smerge(float& m, float& s, float m2, float s2) {
    float nm = fmaxf(m, m2);
    s = s * fexp(m - nm) + s2 * fexp(m2 - nm);
    m = nm;
}

// ---------------- SETUP2: cvt WcW->bf16 | build xaB | bias-preinit | zeros | zero out1 ----------------
__global__ void setup2(const float* __restrict__ WcW, unsigned short* __restrict__ WcB,
                       const int* __restrict__ tok, const float* __restrict__ hidden,
                       const float* __restrict__ emb, unsigned short* __restrict__ xaB,
                       const float* __restrict__ attnb, const float* __restrict__ combb,
                       const float* __restrict__ bih, const float* __restrict__ bhh,
                       float* __restrict__ aT, float* __restrict__ gruOutF,
                       float* __restrict__ giT, float* __restrict__ ghT,
                       float* __restrict__ zeros, float* __restrict__ out1) {
    int idx = blockIdx.x * 256 + threadIdx.x;   // 1478656 total
    if (idx < 262144) {
        float4 v = ((const float4*)WcW)[idx];
        ushort4 o;
        o.x = f2bf(v.x); o.y = f2bf(v.y); o.z = f2bf(v.z); o.w = f2bf(v.w);
        ((ushort4*)WcB)[idx] = o;
        return;
    }
    idx -= 262144;
    if (idx < 98304) {
        int b = idx / 1536, k = idx % 1536;
        float v = (k < EE) ? emb[tok[b] * EE + k] : hidden[b * HH + (k - EE)];
        xaB[b * 1536 + k] = f2bf(v);
        return;
    }
    idx -= 98304;
    if (idx < 8192) { aT[idx] = attnb[idx >> 6]; return; }
    idx -= 8192;
    if (idx < 65536) { gruOutF[idx] = combb[idx >> 6]; return; }
    idx -= 65536;
    if (idx < 196608) { giT[idx] = bih[idx >> 6]; return; }
    idx -= 196608;
    if (idx < 196608) { ghT[idx] = bhh[idx >> 6]; return; }
    idx -= 196608;
    if (idx < 139264) { zeros[idx] = 0.f; return; }
    idx -= 139264;
    int b = idx / 8000, q = idx % 8000;
    ((float4*)(out1 + (size_t)b * MAXV))[q] = (float4){0.f, 0.f, 0.f, 0.f};
}

// ---------------- mgemm body: out[r][b] = sum_k W[r][k] * x[b][k]  (x bf16, W f32->bf16 in-reg) ----------------
template <int DIRECT, int MI>
__device__ __forceinline__ void mgemm_body(int bid,
        const float* __restrict__ W, const float* __restrict__ bias,
        const unsigned short* __restrict__ xA, int sA,
        const unsigned short* __restrict__ xB, int sB, int K1,
        int K, int Kc, int splitk, float* __restrict__ out) {
    int tid = threadIdx.x, w = tid >> 6, lane = tid & 63;
    int rb = bid / splitk, kseg = bid - rb * splitk;
    int r0 = rb * (MI * 64), kb0 = kseg * Kc;
    int lr = lane & 15, lk = lane >> 4;
    int nt = Kc >> 6;
    f32x4 acc[MI][4];
#pragma unroll
    for (int mi = 0; mi < MI; ++mi)
#pragma unroll
        for (int nf = 0; nf < 4; ++nf) acc[mi][nf] = (f32x4){0.f, 0.f, 0.f, 0.f};
    const float* Wr[MI];
#pragma unroll
    for (int mi = 0; mi < MI; ++mi)
        Wr[mi] = W + (size_t)(r0 + w * (MI * 16) + mi * 16 + lr) * K;

    for (int t = 0; t < nt; ++t) {
        int kb = kb0 + t * 64;
        bf16x8 bfr[2][4];
#pragma unroll
        for (int ks = 0; ks < 2; ++ks)
#pragma unroll
            for (int nf = 0; nf < 4; ++nf) {
                int bcol = nf * 16 + lr;
                int kg = kb + ks * 32 + lk * 8;
                const unsigned short* xp = (kg < K1) ? (xA + bcol * sA + kg)
                                                     : (xB + bcol * sB + (kg - K1));
                bfr[ks][nf] = *(const bf16x8*)xp;
            }
        bf16x8 afr[MI][2];
#pragma unroll
        for (int mi = 0; mi < MI; ++mi)
#pragma unroll
            for (int ks = 0; ks < 2; ++ks) {
                const float* wp = Wr[mi] + kb + ks * 32 + lk * 8;
                float4 w0 = *(const float4*)wp;
                float4 w1 = *(const float4*)(wp + 4);
                union { u32x4 u; bf16x8 h; } cv;
                cv.u[0] = pkbf(w0.x, w0.y); cv.u[1] = pkbf(w0.z, w0.w);
                cv.u[2] = pkbf(w1.x, w1.y); cv.u[3] = pkbf(w1.z, w1.w);
                afr[mi][ks] = cv.h;
            }
#pragma unroll
        for (int ks = 0; ks < 2; ++ks)
#pragma unroll
            for (int mi = 0; mi < MI; ++mi)
#pragma unroll
                for (int nf = 0; nf < 4; ++nf)
                    acc[mi][nf] = __builtin_amdgcn_mfma_f32_16x16x32_bf16(
                        afr[mi][ks], bfr[ks][nf], acc[mi][nf], 0, 0, 0);
    }
#pragma unroll
    for (int mi = 0; mi < MI; ++mi)
#pragma unroll
        for (int nf = 0; nf < 4; ++nf)
#pragma unroll
            for (int reg = 0; reg < 4; ++reg) {
                int r = r0 + w * (MI * 16) + mi * 16 + lk * 4 + reg;
                int bcol = nf * 16 + lr;
                float v = acc[mi][nf][reg];
                if (DIRECT) out[r * 64 + bcol] = v + bias[r];
                else atomicAdd(&out[r * 64 + bcol], v);
            }
}

template <int DIRECT, int MI>
__global__ __launch_bounds__(256) void mgemm(
        const float* __restrict__ W, const float* __restrict__ bias,
        const unsigned short* __restrict__ xA, int sA,
        const unsigned short* __restrict__ xB, int sB, int K1,
        int K, int Kc, int splitk, float* __restrict__ out) {
    mgemm_body<DIRECT, MI>(blockIdx.x, W, bias, xA, sA, xB, sB, K1, K, Kc, splitk, out);
}

// ---------------- merged GRU GEMMs: blocks 0..191 Wih (splitk 8), 192..383 Whh (splitk 8) ----------------
__global__ __launch_bounds__(256) void gru2(
        const float* __restrict__ Wih, const float* __restrict__ Whh,
        const unsigned short* __restrict__ gruInB, const unsigned short* __restrict__ xaB512,
        float* __restrict__ giT, float* __restrict__ ghT) {
    const float* W; const unsigned short* x; int s, K1, K, Kc; float* out; int bid;
    if (blockIdx.x < 192) { W = Wih; x = gruInB; s = 2048; K1 = 2048; K = 2048; Kc = 256; out = giT; bid = blockIdx.x; }
    else                  { W = Whh; x = xaB512; s = 1536; K1 = 1024; K = 1024; Kc = 128; out = ghT; bid = blockIdx.x - 192; }
    mgemm_body<0, 2>(bid, W, nullptr, x, s, x, s, K1, K, Kc, 8, out);
}

// ---------------- K2: softmax(a) + sel; stream enc (emit encB bf16), atomic partials ----------------
__global__ __launch_bounds__(256) void k2_softmax_enc(
        const float* __restrict__ aT, const int* __restrict__ tok, const int* __restrict__ seq,
        const float* __restrict__ pprob, const float* __restrict__ enc,
        unsigned short* __restrict__ encB,
        float* __restrict__ ap4T, float* __restrict__ gruSelF, float* __restrict__ out3) {
    int b = blockIdx.x, lc = blockIdx.y, t = threadIdx.x;
    __shared__ float red[256];
    __shared__ float w_s[16], sel_s[16];
    float av = (t < LL) ? aT[t * 64 + b] : -1e30f;
    red[t] = av; __syncthreads();
    for (int s = 128; s > 0; s >>= 1) { if (t < s) red[t] = fmaxf(red[t], red[t + s]); __syncthreads(); }
    float m = red[0]; __syncthreads();
    float e = (t < LL) ? fexp(av - m) : 0.f;
    red[t] = e; __syncthreads();
    for (int s = 128; s > 0; s >>= 1) { if (t < s) red[t] += red[t + s]; __syncthreads(); }
    float Z = red[0]; __syncthreads();
    if (t < LL) {
        float wv = e / Z;
        if (lc == 0) out3[b * LL + t] = wv;
        int l0 = lc * 16;
        if (t >= l0 && t < l0 + 16) {
            w_s[t - l0] = wv;
            sel_s[t - l0] = (seq[b * LL + t] == tok[b]) ? pprob[b * LL + t] : 0.f;
        }
    }
    __syncthreads();
    float accA[4] = {0.f,0.f,0.f,0.f}, accS[4] = {0.f,0.f,0.f,0.f};
    const float* encb = enc + (size_t)b * LL * HH + (size_t)lc * 16 * HH;
    unsigned short* encBb = encB + (size_t)b * LL * HH + (size_t)lc * 16 * HH;
    for (int l = 0; l < 16; ++l) {
        float wl = w_s[l], sl = sel_s[l];
#pragma unroll
        for (int i = 0; i < 4; ++i) {
            float ev = encb[l * HH + t + i * 256];
            encBb[l * HH + t + i * 256] = f2bf(ev);
            accA[i] += wl * ev;
            accS[i] += sl * truncf(ev);
        }
    }
#pragma unroll
    for (int i = 0; i < 4; ++i) {
        int h = t + i * 256;
        atomicAdd(&ap4T[(h >> 2) * 256 + b * 4 + (h & 3)], accA[i]);
        atomicAdd(&gruSelF[(h >> 2) * 256 + b * 4 + (h & 3)], accS[i]);
    }
}

// ---------------- cvt_ap: ap4T (f32 4T) -> apB[b][k] bf16 ----------------
__global__ void cvt_ap(const float* __restrict__ ap4T, unsigned short* __restrict__ apB) {
    int tid = blockIdx.x * 256 + threadIdx.x;  // 16384
    int b = tid & 63, kq = tid >> 6;
    float4 v = *(const float4*)&ap4T[kq * 256 + b * 4];
    ushort4 o;
    o.x = f2bf(v.x); o.y = f2bf(v.y); o.z = f2bf(v.z); o.w = f2bf(v.w);
    *(ushort4*)&apB[b * 1024 + kq * 4] = o;
}

// ---------------- cvt_gruIn: [relu(gruOutF); gruSelF] -> gruInB[b][0..2048) bf16 ----------------
__global__ void cvt_gruIn(const float* __restrict__ gruOutF, const float* __restrict__ gruSelF,
                          unsigned short* __restrict__ gruInB) {
    int tid = blockIdx.x * 256 + threadIdx.x;  // 32768
    int b = tid & 63, kq = tid >> 6;
    float4 v;
    if (kq < 256) {
        int k = kq * 4;
        v.x = fmaxf(gruOutF[(k + 0) * 64 + b], 0.f);
        v.y = fmaxf(gruOutF[(k + 1) * 64 + b], 0.f);
        v.z = fmaxf(gruOutF[(k + 2) * 64 + b], 0.f);
        v.w = fmaxf(gruOutF[(k + 3) * 64 + b], 0.f);
    } else {
        v = *(const float4*)&gruSelF[(kq - 256) * 256 + b * 4];
    }
    ushort4 o;
    o.x = f2bf(v.x); o.y = f2bf(v.y); o.z = f2bf(v.z); o.w = f2bf(v.w);
    *(ushort4*)&gruInB[b * 2048 + kq * 4] = o;
}

// ---------------- K5: GRU gates -> h_new ----------------
__global__ void k5_gates(const float* __restrict__ giT, const float* __restrict__ ghT,
                         const float* __restrict__ hidden, float* __restrict__ hn4T,
                         unsigned short* __restrict__ hnB, float* __restrict__ out2) {
    int idx = blockIdx.x * 256 + threadIdx.x;   // 65536
    int r = idx >> 6, b = idx & 63;
    float ir = giT[r * 64 + b], iz = giT[(HH + r) * 64 + b], in_ = giT[(2 * HH + r) * 64 + b];
    float hr = ghT[r * 64 + b], hz = ghT[(HH + r) * 64 + b], hn = ghT[(2 * HH + r) * 64 + b];
    float rr = 1.f / (1.f + fexp(-(ir + hr)));
    float zz = 1.f / (1.f + fexp(-(iz + hz)));
    float nn = ftanh(in_ + rr * hn);
    float hprev = hidden[b * HH + r];
    float hnew = (1.f - zz) * nn + zz * hprev;
    hn4T[(r >> 2) * 256 + b * 4 + (r & 3)] = hnew;
    hnB[b * 1024 + r] = f2bf(hnew);
    out2[b * HH + r] = hnew;
}

// ---------------- WOW_F1: WoW GEMM, 64 rows/block x 500 blocks; BK=128 LDS-staged W
// (contiguous, XOR-pre-swizzled source); 8 barrier-phases; fused f1 partial ----------------
__global__ __launch_bounds__(256) void wow_f1(
        const float* __restrict__ WoW, const float* __restrict__ Wob,
        const unsigned short* __restrict__ hnB, float* __restrict__ sgT,
        float* __restrict__ partMt, float* __restrict__ partSt) {
    __shared__ __align__(16) float Ws[64 * 128];  // 32 KB: 64 rows x 32 chunks(16B)
    __shared__ float pm_s[4 * 64], ps_s[4 * 64];
    int tid = threadIdx.x, w = tid >> 6, lane = tid & 63;
    int lr = lane & 15, lk = lane >> 4;
    int r0 = blockIdx.x * 64;
    int arow = w * 16 + lr;                       // A-fragment row this lane serves
    int sw = arow & 7;                            // read-side XOR key
    f32x4 acc[4];
#pragma unroll
    for (int nf = 0; nf < 4; ++nf) acc[nf] = (f32x4){0.f, 0.f, 0.f, 0.f};

    for (int kt = 0; kt < 8; ++kt) {              // BK=128: 8 phases
        __syncthreads();
#pragma unroll
        for (int i = 0; i < 8; ++i) {
            int c = i * 256 + tid;
            int row = c >> 5, ch = c & 31;
            int chs = ch ^ (row & 7);
            gload_lds16(WoW + (size_t)(r0 + row) * HH + kt * 128 + chs * 4,
                        (char*)Ws + (i * 256 + w * 64) * 16);
        }
        int kb = kt * 128;
        bf16x8 bfr[4][4];
#pragma unroll
        for (int ks = 0; ks < 4; ++ks)
#pragma unroll
            for (int nf = 0; nf < 4; ++nf)
                bfr[ks][nf] = *(const bf16x8*)(hnB + (nf * 16 + lr) * 1024 + kb + ks * 32 + lk * 8);
        asm volatile("s_waitcnt vmcnt(0)");
        __syncthreads();
#pragma unroll
        for (int ks = 0; ks < 4; ++ks) {
            int c0 = (ks * 8 + lk * 2) ^ sw;
            int c1 = (ks * 8 + lk * 2 + 1) ^ sw;
            float4 w0 = *(const float4*)((const char*)Ws + (arow * 32 + c0) * 16);
            float4 w1 = *(const float4*)((const char*)Ws + (arow * 32 + c1) * 16);
            union { u32x4 u; bf16x8 h; } cv;
            cv.u[0] = pkbf(w0.x, w0.y); cv.u[1] = pkbf(w0.z, w0.w);
            cv.u[2] = pkbf(w1.x, w1.y); cv.u[3] = pkbf(w1.z, w1.w);
#pragma unroll
            for (int nf = 0; nf < 4; ++nf)
                acc[nf] = __builtin_amdgcn_mfma_f32_16x16x32_bf16(cv.h, bfr[ks][nf], acc[nf], 0, 0, 0);
        }
    }
#pragma unroll
    for (int nf = 0; nf < 4; ++nf) {
        int bcol = nf * 16 + lr;
        float m = -1e30f, s = 0.f;
#pragma unroll
        for (int reg = 0; reg < 4; ++reg) {
            int r = r0 + w * 16 + lk * 4 + reg;
            float v = acc[nf][reg] + Wob[r];
            sgT[r * 64 + bcol] = v;
            float nm = fmaxf(m, v);
            s = s * fexp(m - nm) + fexp(v - nm);
            m = nm;
        }
#pragma unroll
        for (int d = 16; d <= 32; d <<= 1) {
            float om = __shfl_xor(m, d), os = __shfl_xor(s, d);
            smerge(m, s, om, os);
        }
        if (lk == 0) { pm_s[w * 64 + bcol] = m; ps_s[w * 64 + bcol] = s; }
    }
    __syncthreads();
    if (tid < 64) {
        float m = pm_s[tid], s = ps_s[tid];
        smerge(m, s, pm_s[64 + tid], ps_s[64 + tid]);
        smerge(m, s, pm_s[128 + tid], ps_s[128 + tid]);
        smerge(m, s, pm_s[192 + tid], ps_s[192 + tid]);
        partMt[tid * 512 + blockIdx.x] = m;
        partSt[tid * 512 + blockIdx.x] = s;
    }
}

// ---------------- K7: MFMA bf16 GEMM + fused tanh*h reduce -> sc; BK=128 (8 phases), XCD swizzle ----------------
__global__ __launch_bounds__(256) void k7_mfma(const unsigned short* __restrict__ encB,
        const unsigned short* __restrict__ WcB, const float* __restrict__ Wcb,
        const float* __restrict__ hn4T, float* __restrict__ sc) {
    __shared__ __align__(16) unsigned short As[128 * 128];   // 32 KB
    __shared__ __align__(16) unsigned short Bs[128 * 128];   // 32 KB
    __shared__ float h_s[128], bias_s[128];
    int tid = threadIdx.x, w = tid >> 6, lane = tid & 63;
    int wm = w >> 1, wn = w & 1;
    int bid = blockIdx.x;
    int swz = (bid & 7) * 64 + (bid >> 3);   // bijective XCD swizzle, 512 = 8*64
    int mt = swz >> 3, nt = swz & 7;
    int m0 = mt * 128, n0 = nt * 128;
    if (tid < 128) {
        int n = n0 + tid;
        bias_s[tid] = Wcb[n];
        h_s[tid] = hn4T[(n >> 2) * 256 + mt * 4 + (n & 3)];
    }
    f32x4 acc[4][4];
#pragma unroll
    for (int mi = 0; mi < 4; ++mi)
#pragma unroll
        for (int ni = 0; ni < 4; ++ni) acc[mi][ni] = (f32x4){0.f, 0.f, 0.f, 0.f};

    for (int kt = 0; kt < 8; ++kt) {             // BK=128: 8 phases
        __syncthreads();
#pragma unroll
        for (int i = 0; i < 8; ++i) {
            int c = i * 256 + tid;
            int row = c >> 4, cc = c & 15;
            int lc2 = cc ^ (row & 7);
            gload_lds16(encB + (size_t)(m0 + row) * HH + kt * 128 + lc2 * 8,
                        (char*)As + (i * 256 + w * 64) * 16);
        }
#pragma unroll
        for (int i = 0; i < 8; ++i) {
            int c = i * 256 + tid;
            int row = c >> 4, cc = c & 15;
            int lc2 = cc ^ (row & 7);
            gload_lds16(WcB + (size_t)(n0 + row) * HH + kt * 128 + lc2 * 8,
                        (char*)Bs + (i * 256 + w * 64) * 16);
        }
        asm volatile("s_waitcnt vmcnt(0)");
        __syncthreads();
#pragma unroll
        for (int ks = 0; ks < 4; ++ks) {
            bf16x8 af[4], bf[4];
#pragma unroll
            for (int mi = 0; mi < 4; ++mi) {
                int rr = wm * 64 + mi * 16 + (lane & 15);
                int lkk = ks * 4 + (lane >> 4);
                af[mi] = *(const bf16x8*)((const char*)As + rr * 256 + ((lkk ^ (rr & 7)) * 16));
            }
#pragma unroll
            for (int ni = 0; ni < 4; ++ni) {
                int rr = wn * 64 + ni * 16 + (lane & 15);
                int lkk = ks * 4 + (lane >> 4);
                bf[ni] = *(const bf16x8*)((const char*)Bs + rr * 256 + ((lkk ^ (rr & 7)) * 16));
            }
#pragma unroll
            for (int mi = 0; mi < 4; ++mi)
#pragma unroll
                for (int ni = 0; ni < 4; ++ni)
                    acc[mi][ni] = __builtin_amdgcn_mfma_f32_16x16x32_bf16(af[mi], bf[ni], acc[mi][ni], 0, 0, 0);
        }
    }
    float rs[16];
#pragma unroll
    for (int z = 0; z < 16; ++z) rs[z] = 0.f;
#pragma unroll
    for (int ni = 0; ni < 4; ++ni) {
        int nl = wn * 64 + ni * 16 + (lane & 15);
        float hv = h_s[nl], bv = bias_s[nl];
#pragma unroll
        for (int mi = 0; mi < 4; ++mi)
#pragma unroll
            for (int reg = 0; reg < 4; ++reg)
                rs[mi * 4 + reg] += ftanh(acc[mi][ni][reg] + bv) * hv;
    }
#pragma unroll
    for (int z = 0; z < 16; ++z) {
        float v = rs[z];
        v += __shfl_xor(v, 1); v += __shfl_xor(v, 2);
        v += __shfl_xor(v, 4); v += __shfl_xor(v, 8);
        rs[z] = v;
    }
    if ((lane & 15) == 0) {
        int g = lane >> 4;
#pragma unroll
        for (int mi = 0; mi < 4; ++mi)
#pragma unroll
            for (int reg = 0; reg < 4; ++reg)
                atomicAdd(&sc[mt * LL + wm * 64 + mi * 16 + g * 4 + reg], rs[mi * 4 + reg]);
    }
}

// ---------------- F1c: tree-combine partials + sc -> M,Z ; write out4 + scatter into out1 ----------------
__global__ __launch_bounds__(256) void f1c_final(const float* __restrict__ partMt,
        const float* __restrict__ partSt, const float* __restrict__ sc,
        const int* __restrict__ seq, float* __restrict__ Mb, float* __restrict__ Zb,
        float* __restrict__ out4, float* __restrict__ out1) {
    int b = blockIdx.x, t = threadIdx.x;
    __shared__ float mred[256], sred[256];
    float m = -1e30f, s = 0.f;
    for (int w = t; w < 500; w += 256)
        smerge(m, s, partMt[b * 512 + w], partSt[b * 512 + w]);
    if (t < 128) smerge(m, s, sc[b * LL + t], 1.0f);
    mred[t] = m; sred[t] = s; __syncthreads();
    for (int st = 128; st > 0; st >>= 1) {
        if (t < st) {
            float mm = mred[t], ss = sred[t];
            smerge(mm, ss, mred[t + st], sred[t + st]);
            mred[t] = mm; sred[t] = ss;
        }
        __syncthreads();
    }
    float M = mred[0], Z = sred[0];
    if (t == 0) { Mb[b] = M; Zb[b] = Z; }
    if (t < 128) {
        float p = fexp(sc[b * LL + t] - M) / Z;
        out4[b * LL + t] = p;
        atomicAdd(&out1[(size_t)b * MAXV + seq[b * LL + t]], p);
    }
}

// ---------------- F2F4: prob_g + scatter-sum, floor, col2, log -> out1 (single pass) ----------------
__global__ void f2f4_final(const float* __restrict__ sgT, const float* __restrict__ Mb,
                           const float* __restrict__ Zb, float* __restrict__ out1) {
    int b = blockIdx.y;
    int v = blockIdx.x * 256 + threadIdx.x;
    if (v >= MAXV) return;
    float val = 0.f;
    if (v < VV) {
        float scat = out1[(size_t)b * MAXV + v];
        val = fexp(sgT[v * 64 + b] - Mb[b]) / Zb[b] + scat;
    }
    if (v == 2 || val == 0.f) val = 1e-9f;
    out1[(size_t)b * MAXV + v] = flog(val);
}

extern "C" void kernel_launch(void* const* d_in, const int* in_sizes, int n_in,
                              void* d_out, int out_size, void* d_ws, size_t ws_size,
                              hipStream_t stream) {
    (void)in_sizes; (void)n_in; (void)out_size; (void)ws_size;
    const int*   tok    = (const int*)  d_in[0];
    const float* hidden = (const float*)d_in[1];
    const float* enc    = (const float*)d_in[2];
    const int*   seq    = (const int*)  d_in[3];
    const float* pprob  = (const float*)d_in[4];
    const float* emb    = (const float*)d_in[5];
    const float* attnW  = (const float*)d_in[6];
    const float* attnb  = (const float*)d_in[7];
    const float* combW  = (const float*)d_in[8];
    const float* combb  = (const float*)d_in[9];
    const float* Wih    = (const float*)d_in[10];
    const float* Whh    = (const float*)d_in[11];
    const float* bih    = (const float*)d_in[12];
    const float* bhh    = (const float*)d_in[13];
    const float* WoW    = (const float*)d_in[14];
    const float* Wob    = (const float*)d_in[15];
    const float* WcW    = (const float*)d_in[16];
    const float* Wcb    = (const float*)d_in[17];

    float* out1 = (float*)d_out;
    float* out2 = out1 + (size_t)BB * MAXV;
    float* out3 = out2 + BB * HH;
    float* out4 = out3 + BB * LL;

    float* ws      = (float*)d_ws;
    float* aT      = ws;                    // 8192
    float* ap4T    = ws + 8192;             // 65536  (zero region start)
    float* gruSelF = ws + 73728;            // 65536
    float* sc      = ws + 139264;           // 8192   (zero region len 139264)
    float* gruOutF = ws + 147456;           // 65536
    float* giT     = ws + 212992;           // 196608
    float* ghT     = ws + 409600;           // 196608
    float* hn4T    = ws + 606208;           // 65536
    float* sgT     = ws + 671744;           // 2048000
    float* partMt  = ws + 2719744;          // 32768 (64 x 512)
    float* partSt  = ws + 2752512;          // 32768
    float* Mb      = ws + 2785280;          // 64
    float* Zb      = ws + 2785344;          // 64
    unsigned short* encB = (unsigned short*)(ws + 2785408);   // 8388608 bf16 -> f 6979712
    unsigned short* WcB  = encB + 8388608;                    // 1048576 bf16 -> f 7504000
    unsigned short* hnB  = (unsigned short*)(ws + 7504000);   // 65536 bf16 -> f 7536768
    // transient bf16 x-buffers inside sgT region (consumed before sgT is written)
    unsigned short* xaB    = (unsigned short*)sgT;            // 98304 bf16 (f 671744..720896)
    unsigned short* apB    = (unsigned short*)(ws + 720896);  // 65536 bf16 (..753664)
    unsigned short* gruInB = (unsigned short*)(ws + 753664);  // 131072 bf16 (..819200)

    setup2       <<<5776, 256, 0, stream>>>(WcW, WcB, tok, hidden, emb, xaB,
                                            attnb, combb, bih, bhh,
                                            aT, gruOutF, giT, ghT, ap4T, out1);
    mgemm<0,2>   <<<12, 256, 0, stream>>>(attnW, nullptr, xaB, 1536, xaB, 1536, 1536, 1536, 128, 12, aT);
    k2_softmax_enc<<<dim3(64, 8), 256, 0, stream>>>(aT, tok, seq, pprob, enc, encB, ap4T, gruSelF, out3);
    cvt_ap       <<<64, 256, 0, stream>>>(ap4T, apB);
    mgemm<0,2>   <<<96, 256, 0, stream>>>(combW, nullptr, xaB, 1536, apB, 1024, 512, 1536, 128, 12, gruOutF);
    cvt_gruIn    <<<128, 256, 0, stream>>>(gruOutF, gruSelF, gruInB);
    gru2         <<<384, 256, 0, stream>>>(Wih, Whh, gruInB, xaB + 512, giT, ghT);
    k5_gates     <<<256, 256, 0, stream>>>(giT, ghT, hidden, hn4T, hnB, out2);
    wow_f1       <<<500, 256, 0, stream>>>(WoW, Wob, hnB, sgT, partMt, partSt);
    k7_mfma      <<<512, 256, 0, stream>>>(encB, WcB, Wcb, hn4T, sc);
    f1c_final    <<<64, 256, 0, stream>>>(partMt, partSt, sc, seq, Mb, Zb, out4, out1);
    f2f4_final   <<<dim3(129, 64), 256, 0, stream>>>(sgT, Mb, Zb, out1);
}